// Round 11
// baseline (336.779 us; speedup 1.0000x reference)
//
#include <hip/hip_runtime.h>
#include <hip/hip_bf16.h>

#define NN 50000
#define NE 800000
#define IN_CH 64
#define HID 128
#define NL 4
#define LN_EPS 1e-5f

// padded CSR capacity: NE + 7*NN = 1,150,000
#define ECAP 1150000
#define WSCALE 1048576.0f   // 2^20 fixed point for edge-weight sums
#define VSCALE 32767.0f     // Q15 for packed edge values
#define PKS 8               // pk stride in u64 (one node per 64B line)

typedef __attribute__((ext_vector_type(8))) short s8v;
typedef __attribute__((ext_vector_type(4))) float f4v;
typedef __attribute__((ext_vector_type(4))) uint u4v;

__device__ inline ushort f2bf(float x) {
    __hip_bfloat16 h = __float2bfloat16(x);
    return *(ushort*)&h;
}
__device__ inline float2 bfu(uint u) {
    union { uint i; float f; } a, b;
    a.i = u << 16;
    b.i = u & 0xffff0000u;
    return make_float2(a.f, b.f);
}

// ---------------- preprocessing ----------------

__global__ void k_zero(int4* __restrict__ p, int n4) {
    int i = blockIdx.x * blockDim.x + threadIdx.x;
    if (i < n4) p[i] = make_int4(0, 0, 0, 0);
}

// one packed 64-bit atomic per edge: hi32 = count, lo32 = Q20 weight sum.
__global__ void k_deg_cnt(const int* __restrict__ ei, const float* __restrict__ ew,
                          unsigned long long* __restrict__ pk, int* __restrict__ ord) {
    int e = blockIdx.x * blockDim.x + threadIdx.x;
    if (e >= NE) return;
    int d = ei[NE + e];
    unsigned int wq = (unsigned int)__float2uint_rn(ew[e] * WSCALE);
    unsigned long long old = atomicAdd(&pk[(size_t)d * PKS],
                                       (1ULL << 32) | (unsigned long long)wq);
    ord[e] = (int)(old >> 32);
}

// hierarchical scan of padded counts ((cnt+7)&~7) -> rowp (exclusive); fused dinv
__global__ __launch_bounds__(1024) void k_scan_a(const unsigned long long* __restrict__ pk,
                                                 int* __restrict__ rowp_tmp,
                                                 int* __restrict__ bsum,
                                                 float* __restrict__ dinv) {
    __shared__ int wsum[16];
    int tid = threadIdx.x;
    int lane = tid & 63, wv = tid >> 6;
    int i = blockIdx.x * 1024 + tid;
    unsigned long long pv = (i < NN) ? pk[(size_t)i * PKS] : 0ULL;
    if (i < NN) {
        float deg = (float)(unsigned int)(pv & 0xffffffffu) * (1.0f / WSCALE);
        dinv[i] = rsqrtf(deg + 1.0f);
    }
    int v = (((int)(pv >> 32) + 7) & ~7);
    int s = v;
#pragma unroll
    for (int off = 1; off < 64; off <<= 1) {
        int t = __shfl_up(s, off, 64);
        if (lane >= off) s += t;
    }
    if (lane == 63) wsum[wv] = s;
    __syncthreads();
    int woff = 0;
    for (int w = 0; w < wv; w++) woff += wsum[w];
    if (i < NN) rowp_tmp[i] = woff + s - v;
    if (tid == 1023) bsum[blockIdx.x] = woff + s;
}

__global__ __launch_bounds__(64) void k_scan_b(const int* __restrict__ bsum,
                                               int* __restrict__ boff,
                                               int* __restrict__ rowp, int nb) {
    int t = threadIdx.x;
    int v = (t < nb) ? bsum[t] : 0;
    int s = v;
#pragma unroll
    for (int off = 1; off < 64; off <<= 1) {
        int u = __shfl_up(s, off, 64);
        if (t >= off) s += u;
    }
    if (t < nb) boff[t] = s - v;
    if (t == 63) rowp[NN] = s;
}

// phase c: finalize rowp AND zero the padding slots (fused k_pad)
__global__ __launch_bounds__(1024) void k_scan_c(const int* __restrict__ rowp_tmp,
                                                 const int* __restrict__ boff,
                                                 const unsigned long long* __restrict__ pk,
                                                 int* __restrict__ rowp,
                                                 uint* __restrict__ erec) {
    int i = blockIdx.x * 1024 + threadIdx.x;
    if (i >= NN) return;
    int start = rowp_tmp[i] + boff[blockIdx.x];
    rowp[i] = start;
    int cnt = (int)(pk[(size_t)i * PKS] >> 32);
    int v = (cnt + 7) & ~7;
    for (int p = start + cnt; p < start + v; p++) erec[p] = 0u;
}

// atomic-free scatter: pos = rowp[d] + ord[e]; one u32 record (src<<15 | Q15 val)
__global__ void k_scatter(const int* __restrict__ ei, const float* __restrict__ ew,
                          const float* __restrict__ dinv, const int* __restrict__ rowp,
                          const int* __restrict__ ord, uint* __restrict__ erec) {
    int e = blockIdx.x * blockDim.x + threadIdx.x;
    if (e >= NE) return;
    int s = ei[e];
    int d = ei[NE + e];
    int pos = rowp[d] + ord[e];
    float v = dinv[s] * ew[e] * dinv[d];               // in (0, 1]
    uint q = (uint)__float2int_rn(v * VSCALE);
    erec[pos] = ((uint)s << 15) | q;
}

// ---------------- W repack for MFMA: all layers at once ----------------
__global__ __launch_bounds__(256) void k_wpack(const float* __restrict__ cW,
                                               ushort* __restrict__ Wp) {
    int gid = blockIdx.x * 256 + threadIdx.x;          // 0 .. 8191
    int lane = gid & 63;
    int t = (gid >> 6) & 7;
    int kc = (gid >> 9) & 3;
    int layer = gid >> 11;
    const float* W = cW + (size_t)layer * HID * HID;
    int kbase = kc * 32 + (lane >> 4) * 8;
    int col = t * 16 + (lane & 15);
    ushort o[8];
#pragma unroll
    for (int j = 0; j < 8; j++) o[j] = f2bf(W[(size_t)(kbase + j) * HID + col]);
    uint4 pk4;
    pk4.x = (uint)o[0] | ((uint)o[1] << 16);
    pk4.y = (uint)o[2] | ((uint)o[3] << 16);
    pk4.z = (uint)o[4] | ((uint)o[5] << 16);
    pk4.w = (uint)o[6] | ((uint)o[7] << 16);
    ((uint4*)Wp)[gid] = pk4;
}

// ---------------- input projection: h = relu(x @ W_in + b_in) ----------------
__global__ __launch_bounds__(256) void k_inproj(const float* __restrict__ x,
                                                const float* __restrict__ W,
                                                const float* __restrict__ b,
                                                float* __restrict__ h) {
    __shared__ float xs[64][IN_CH];
    int tid = threadIdx.x;
    int cx = tid & 31;
    int ny = tid >> 5;
    int nbase = blockIdx.x * 64;
    const float4* xg = (const float4*)(x + (size_t)nbase * IN_CH);
    float4* xs4 = (float4*)xs;
#pragma unroll
    for (int p = 0; p < 4; p++) {
        int i = p * 256 + tid;
        int row = i >> 4;
        xs4[i] = (nbase + row < NN) ? xg[i] : make_float4(0, 0, 0, 0);
    }
    __syncthreads();
    float4 acc[8];
#pragma unroll
    for (int j = 0; j < 8; j++) acc[j] = make_float4(0, 0, 0, 0);
    const float4* W4 = (const float4*)W;
#pragma unroll 4
    for (int k4 = 0; k4 < IN_CH / 4; k4++) {
        int k = 4 * k4;
        float4 w0 = W4[(k + 0) * 32 + cx];
        float4 w1 = W4[(k + 1) * 32 + cx];
        float4 w2 = W4[(k + 2) * 32 + cx];
        float4 w3 = W4[(k + 3) * 32 + cx];
#pragma unroll
        for (int j = 0; j < 8; j++) {
            float4 hv = *(const float4*)&xs[ny * 8 + j][k];
            acc[j].x += hv.x * w0.x + hv.y * w1.x + hv.z * w2.x + hv.w * w3.x;
            acc[j].y += hv.x * w0.y + hv.y * w1.y + hv.z * w2.y + hv.w * w3.y;
            acc[j].z += hv.x * w0.z + hv.y * w1.z + hv.z * w2.z + hv.w * w3.z;
            acc[j].w += hv.x * w0.w + hv.y * w1.w + hv.z * w2.w + hv.w * w3.w;
        }
    }
    float4 bc = ((const float4*)b)[cx];
    float4* mg = (float4*)h;
#pragma unroll
    for (int j = 0; j < 8; j++) {
        int n = nbase + ny * 8 + j;
        if (n < NN) {
            float4 o;
            o.x = fmaxf(acc[j].x + bc.x, 0.f);
            o.y = fmaxf(acc[j].y + bc.y, 0.f);
            o.z = fmaxf(acc[j].z + bc.z, 0.f);
            o.w = fmaxf(acc[j].w + bc.w, 0.f);
            mg[n * 32 + cx] = o;
        }
    }
}

// ---------------- per-layer GEMM via MFMA: m(bf16) = h(f32->bf16) @ W_l ----------------
__global__ __launch_bounds__(256) void k_gemm(const float* __restrict__ h,
                                              const ushort* __restrict__ Wp,
                                              ushort* __restrict__ m) {
    int tid = threadIdx.x;
    int w = tid >> 6, l = tid & 63;
    int q = l >> 4, r16 = l & 15;
    int rowbase = blockIdx.x * 64 + w * 16;
    f4v acc[8];
#pragma unroll
    for (int t = 0; t < 8; t++) acc[t] = (f4v){0.f, 0.f, 0.f, 0.f};
    const s8v* wp = (const s8v*)Wp;
#pragma unroll
    for (int kc = 0; kc < 4; kc++) {
        int row = rowbase + r16;
        s8v afrag;
        if (row < NN) {
            const float4* hp = (const float4*)(h + (size_t)row * HID + kc * 32 + q * 8);
            float4 h0 = hp[0], h1 = hp[1];
            afrag[0] = (short)f2bf(h0.x); afrag[1] = (short)f2bf(h0.y);
            afrag[2] = (short)f2bf(h0.z); afrag[3] = (short)f2bf(h0.w);
            afrag[4] = (short)f2bf(h1.x); afrag[5] = (short)f2bf(h1.y);
            afrag[6] = (short)f2bf(h1.z); afrag[7] = (short)f2bf(h1.w);
        } else {
            afrag = (s8v){0, 0, 0, 0, 0, 0, 0, 0};
        }
#pragma unroll
        for (int t = 0; t < 8; t++) {
            s8v bfrag = wp[(kc * 8 + t) * 64 + l];
            acc[t] = __builtin_amdgcn_mfma_f32_16x16x32_bf16(afrag, bfrag, acc[t], 0, 0, 0);
        }
    }
    // C/D layout: col = l&15, row = (l>>4)*4 + reg
#pragma unroll
    for (int t = 0; t < 8; t++) {
#pragma unroll
        for (int rg = 0; rg < 4; rg++) {
            int orow = rowbase + q * 4 + rg;
            if (orow < NN) m[(size_t)orow * HID + t * 16 + r16] = f2bf(acc[t][rg]);
        }
    }
}

// ---------------- aggregate + bias + LN + relu + residual (in-place h) ----------------
// one wave per node, 2 half-waves gather different edges' rows (uint2 = 4 bf16 ch/lane).
// 8 edges/iter; record/rowp loads are non-temporal (streaming) to protect m's L2 residency.
__global__ __launch_bounds__(256) void k_agg(const ushort* __restrict__ m,
                                             const int* __restrict__ rowp,
                                             const uint* __restrict__ erec,
                                             const float* __restrict__ dinv,
                                             const float* __restrict__ cb,
                                             const float* __restrict__ g,
                                             const float* __restrict__ bb,
                                             float* __restrict__ h) {
    int lane = threadIdx.x & 63;
    int sub = lane & 31;           // channel quad: 4*sub..4*sub+3
    int hi = lane >> 5;            // which edge of the pair
    int n = blockIdx.x * 4 + (threadIdx.x >> 6);
    if (n >= NN) return;
    const uint2* mu2 = (const uint2*)m;
    float dn = dinv[n];
    float selfs = hi ? 0.0f : dn * dn;
    uint2 svu = mu2[(size_t)n * 32 + sub];
    float2 svl = bfu(svu.x), svh = bfu(svu.y);
    float4 a0, a1, a2, a3;
    a0.x = selfs * svl.x; a0.y = selfs * svl.y; a0.z = selfs * svh.x; a0.w = selfs * svh.y;
    a1 = make_float4(0, 0, 0, 0);
    a2 = make_float4(0, 0, 0, 0);
    a3 = make_float4(0, 0, 0, 0);
    int r0 = __builtin_nontemporal_load(rowp + n);
    int r1 = __builtin_nontemporal_load(rowp + n + 1);   // multiples of 8
    const u4v* e4 = (const u4v*)erec;
    for (int r = r0; r < r1; r += 8) {
        int qb = r >> 2;
        u4v rA = __builtin_nontemporal_load(e4 + qb);      // edges r .. r+3
        u4v rB = __builtin_nontemporal_load(e4 + qb + 1);  // edges r+4 .. r+7
        uint c0 = hi ? rA[1] : rA[0];
        uint c1 = hi ? rA[3] : rA[2];
        uint c2 = hi ? rB[1] : rB[0];
        uint c3 = hi ? rB[3] : rB[2];
        int s0 = c0 >> 15;  float v0 = (float)(c0 & 32767u) * (1.0f / VSCALE);
        int s1 = c1 >> 15;  float v1 = (float)(c1 & 32767u) * (1.0f / VSCALE);
        int s2 = c2 >> 15;  float v2 = (float)(c2 & 32767u) * (1.0f / VSCALE);
        int s3 = c3 >> 15;  float v3 = (float)(c3 & 32767u) * (1.0f / VSCALE);
        uint2 g0 = mu2[(size_t)s0 * 32 + sub];
        uint2 g1 = mu2[(size_t)s1 * 32 + sub];
        uint2 g2 = mu2[(size_t)s2 * 32 + sub];
        uint2 g3 = mu2[(size_t)s3 * 32 + sub];
        float2 f0l = bfu(g0.x), f0h = bfu(g0.y);
        float2 f1l = bfu(g1.x), f1h = bfu(g1.y);
        float2 f2l = bfu(g2.x), f2h = bfu(g2.y);
        float2 f3l = bfu(g3.x), f3h = bfu(g3.y);
        a0.x += v0 * f0l.x; a0.y += v0 * f0l.y; a0.z += v0 * f0h.x; a0.w += v0 * f0h.y;
        a1.x += v1 * f1l.x; a1.y += v1 * f1l.y; a1.z += v1 * f1h.x; a1.w += v1 * f1h.y;
        a2.x += v2 * f2l.x; a2.y += v2 * f2l.y; a2.z += v2 * f2h.x; a2.w += v2 * f2h.y;
        a3.x += v3 * f3l.x; a3.y += v3 * f3l.y; a3.z += v3 * f3h.x; a3.w += v3 * f3h.y;
    }
    float4 acc;
    acc.x = a0.x + a1.x + a2.x + a3.x;
    acc.y = a0.y + a1.y + a2.y + a3.y;
    acc.z = a0.z + a1.z + a2.z + a3.z;
    acc.w = a0.w + a1.w + a2.w + a3.w;
    // combine the two half-wave partial sums (lane l <-> l^32)
    acc.x += __shfl_xor(acc.x, 32, 64);
    acc.y += __shfl_xor(acc.y, 32, 64);
    acc.z += __shfl_xor(acc.z, 32, 64);
    acc.w += __shfl_xor(acc.w, 32, 64);
    float4 cbv = ((const float4*)cb)[sub];
    acc.x += cbv.x; acc.y += cbv.y; acc.z += cbv.z; acc.w += cbv.w;
    // LayerNorm over 128 channels: reduce across 32 lanes (both halves identical)
    float s1 = acc.x + acc.y + acc.z + acc.w;
    float s2 = acc.x * acc.x + acc.y * acc.y + acc.z * acc.z + acc.w * acc.w;
#pragma unroll
    for (int off = 16; off > 0; off >>= 1) {
        s1 += __shfl_down(s1, off, 32);
        s2 += __shfl_down(s2, off, 32);
    }
    s1 = __shfl(s1, 0, 32);
    s2 = __shfl(s2, 0, 32);
    float mu = s1 * (1.0f / HID);
    float var = s2 * (1.0f / HID) - mu * mu;
    float rs = rsqrtf(var + LN_EPS);
    if (hi == 0) {
        float4 gv = ((const float4*)g)[sub];
        float4 bv = ((const float4*)bb)[sub];
        float4* h4 = (float4*)h;
        float4 hv = h4[(size_t)n * 32 + sub];
        float4 o;
        o.x = fmaxf((acc.x - mu) * rs * gv.x + bv.x, 0.f) + hv.x;
        o.y = fmaxf((acc.y - mu) * rs * gv.y + bv.y, 0.f) + hv.y;
        o.z = fmaxf((acc.z - mu) * rs * gv.z + bv.z, 0.f) + hv.z;
        o.w = fmaxf((acc.w - mu) * rs * gv.w + bv.w, 0.f) + hv.w;
        h4[(size_t)n * 32 + sub] = o;
    }
}

// ---------------- launch ----------------

extern "C" void kernel_launch(void* const* d_in, const int* in_sizes, int n_in,
                              void* d_out, int out_size, void* d_ws, size_t ws_size,
                              hipStream_t stream) {
    const float* x    = (const float*)d_in[0];
    const int*   ei   = (const int*)d_in[1];
    const float* ew   = (const float*)d_in[2];
    const float* W_in = (const float*)d_in[3];
    const float* b_in = (const float*)d_in[4];
    const float* cW   = (const float*)d_in[5];
    const float* cb   = (const float*)d_in[6];
    const float* lg   = (const float*)d_in[7];
    const float* lb   = (const float*)d_in[8];
    float* h = (float*)d_out;

    char* ws = (char*)d_ws;
    unsigned long long* pk = (unsigned long long*)(ws + 0);   // 50000*64B padded (3.2 MB)
    int*    rowp     = (int*)   (ws + 3200000);               // 50001
    int*    rowp_tmp = (int*)   (ws + 3400064);
    int*    bsum     = (int*)   (ws + 3600064);               // 64
    int*    boff     = (int*)   (ws + 3600320);               // 64
    uint*   erec     = (uint*)  (ws + 3600576);               // ECAP u32 (4.6 MB)
    float*  dinv     = (float*) (ws + 8200576);               // 50000 f32
    ushort* Wp       = (ushort*)(ws + 8400576);               // 4*16384 bf16 (128 KB)
    ushort* m        = (ushort*)(ws + 8531648);               // 50000*128 bf16 (12.8 MB)
    int*    ord      = (int*)   (ws + 8531648);               // aliases m (dead until gemm)

    const int NB = (NN + 1023) / 1024;                        // 49

    k_zero<<<(3200000 / 16 + 255) / 256, 256, 0, stream>>>((int4*)pk, 3200000 / 16);
    k_deg_cnt<<<(NE + 255) / 256, 256, 0, stream>>>(ei, ew, pk, ord);
    k_scan_a<<<NB, 1024, 0, stream>>>(pk, rowp_tmp, bsum, dinv);
    k_scan_b<<<1, 64, 0, stream>>>(bsum, boff, rowp, NB);
    k_scan_c<<<NB, 1024, 0, stream>>>(rowp_tmp, boff, pk, rowp, erec);
    k_scatter<<<(NE + 255) / 256, 256, 0, stream>>>(ei, ew, dinv, rowp, ord, erec);
    k_wpack<<<32, 256, 0, stream>>>(cW, Wp);

    k_inproj<<<(NN + 63) / 64, 256, 0, stream>>>(x, W_in, b_in, h);

    for (int l = 0; l < NL; l++) {
        k_gemm<<<(NN + 63) / 64, 256, 0, stream>>>(h, Wp + (size_t)l * 16384, m);
        k_agg<<<(NN + 3) / 4, 256, 0, stream>>>(m, rowp, erec, dinv,
                                                cb + l * HID, lg + l * HID, lb + l * HID, h);
    }
}

// Round 12
// 336.476 us; speedup vs baseline: 1.0009x; 1.0009x over previous
//
#include <hip/hip_runtime.h>
#include <hip/hip_bf16.h>

#define NN 50000
#define NE 800000
#define IN_CH 64
#define HID 128
#define NL 4
#define LN_EPS 1e-5f

// padded CSR capacity: NE + 7*NN = 1,150,000
#define ECAP 1150000
#define WSCALE 1048576.0f   // 2^20 fixed point for edge-weight sums
#define VSCALE 32767.0f     // Q15 for packed edge values
#define PKS 8               // pk stride in u64 (one node per 64B line)

typedef __attribute__((ext_vector_type(8))) short s8v;
typedef __attribute__((ext_vector_type(4))) float f4v;

__device__ inline ushort f2bf(float x) {
    __hip_bfloat16 h = __float2bfloat16(x);
    return *(ushort*)&h;
}
__device__ inline float2 bfu(uint u) {
    union { uint i; float f; } a, b;
    a.i = u << 16;
    b.i = u & 0xffff0000u;
    return make_float2(a.f, b.f);
}

// ---------------- preprocessing ----------------

__global__ void k_zero(int4* __restrict__ p, int n4) {
    int i = blockIdx.x * blockDim.x + threadIdx.x;
    if (i < n4) p[i] = make_int4(0, 0, 0, 0);
}

// one packed 64-bit atomic per edge: hi32 = count, lo32 = Q20 weight sum.
__global__ void k_deg_cnt(const int* __restrict__ ei, const float* __restrict__ ew,
                          unsigned long long* __restrict__ pk, int* __restrict__ ord) {
    int e = blockIdx.x * blockDim.x + threadIdx.x;
    if (e >= NE) return;
    int d = ei[NE + e];
    unsigned int wq = (unsigned int)__float2uint_rn(ew[e] * WSCALE);
    unsigned long long old = atomicAdd(&pk[(size_t)d * PKS],
                                       (1ULL << 32) | (unsigned long long)wq);
    ord[e] = (int)(old >> 32);
}

// hierarchical scan of padded counts ((cnt+7)&~7) -> rowp (exclusive); fused dinv
__global__ __launch_bounds__(1024) void k_scan_a(const unsigned long long* __restrict__ pk,
                                                 int* __restrict__ rowp_tmp,
                                                 int* __restrict__ bsum,
                                                 float* __restrict__ dinv) {
    __shared__ int wsum[16];
    int tid = threadIdx.x;
    int lane = tid & 63, wv = tid >> 6;
    int i = blockIdx.x * 1024 + tid;
    unsigned long long pv = (i < NN) ? pk[(size_t)i * PKS] : 0ULL;
    if (i < NN) {
        float deg = (float)(unsigned int)(pv & 0xffffffffu) * (1.0f / WSCALE);
        dinv[i] = rsqrtf(deg + 1.0f);
    }
    int v = (((int)(pv >> 32) + 7) & ~7);
    int s = v;
#pragma unroll
    for (int off = 1; off < 64; off <<= 1) {
        int t = __shfl_up(s, off, 64);
        if (lane >= off) s += t;
    }
    if (lane == 63) wsum[wv] = s;
    __syncthreads();
    int woff = 0;
    for (int w = 0; w < wv; w++) woff += wsum[w];
    if (i < NN) rowp_tmp[i] = woff + s - v;
    if (tid == 1023) bsum[blockIdx.x] = woff + s;
}

__global__ __launch_bounds__(64) void k_scan_b(const int* __restrict__ bsum,
                                               int* __restrict__ boff,
                                               int* __restrict__ rowp, int nb) {
    int t = threadIdx.x;
    int v = (t < nb) ? bsum[t] : 0;
    int s = v;
#pragma unroll
    for (int off = 1; off < 64; off <<= 1) {
        int u = __shfl_up(s, off, 64);
        if (t >= off) s += u;
    }
    if (t < nb) boff[t] = s - v;
    if (t == 63) rowp[NN] = s;
}

// phase c: finalize rowp AND zero the padding slots (fused k_pad)
__global__ __launch_bounds__(1024) void k_scan_c(const int* __restrict__ rowp_tmp,
                                                 const int* __restrict__ boff,
                                                 const unsigned long long* __restrict__ pk,
                                                 int* __restrict__ rowp,
                                                 uint* __restrict__ erec) {
    int i = blockIdx.x * 1024 + threadIdx.x;
    if (i >= NN) return;
    int start = rowp_tmp[i] + boff[blockIdx.x];
    rowp[i] = start;
    int cnt = (int)(pk[(size_t)i * PKS] >> 32);
    int v = (cnt + 7) & ~7;
    for (int p = start + cnt; p < start + v; p++) erec[p] = 0u;
}

// atomic-free scatter: pos = rowp[d] + ord[e]; one u32 record (src<<15 | Q15 val)
__global__ void k_scatter(const int* __restrict__ ei, const float* __restrict__ ew,
                          const float* __restrict__ dinv, const int* __restrict__ rowp,
                          const int* __restrict__ ord, uint* __restrict__ erec) {
    int e = blockIdx.x * blockDim.x + threadIdx.x;
    if (e >= NE) return;
    int s = ei[e];
    int d = ei[NE + e];
    int pos = rowp[d] + ord[e];
    float v = dinv[s] * ew[e] * dinv[d];               // in (0, 1]
    uint q = (uint)__float2int_rn(v * VSCALE);
    erec[pos] = ((uint)s << 15) | q;
}

// ---------------- W repack for MFMA: all layers at once ----------------
__global__ __launch_bounds__(256) void k_wpack(const float* __restrict__ cW,
                                               ushort* __restrict__ Wp) {
    int gid = blockIdx.x * 256 + threadIdx.x;          // 0 .. 8191
    int lane = gid & 63;
    int t = (gid >> 6) & 7;
    int kc = (gid >> 9) & 3;
    int layer = gid >> 11;
    const float* W = cW + (size_t)layer * HID * HID;
    int kbase = kc * 32 + (lane >> 4) * 8;
    int col = t * 16 + (lane & 15);
    ushort o[8];
#pragma unroll
    for (int j = 0; j < 8; j++) o[j] = f2bf(W[(size_t)(kbase + j) * HID + col]);
    uint4 pk4;
    pk4.x = (uint)o[0] | ((uint)o[1] << 16);
    pk4.y = (uint)o[2] | ((uint)o[3] << 16);
    pk4.z = (uint)o[4] | ((uint)o[5] << 16);
    pk4.w = (uint)o[6] | ((uint)o[7] << 16);
    ((uint4*)Wp)[gid] = pk4;
}

// ---------------- input projection: h = relu(x @ W_in + b_in); also hb (bf16) ----------------
__global__ __launch_bounds__(256) void k_inproj(const float* __restrict__ x,
                                                const float* __restrict__ W,
                                                const float* __restrict__ b,
                                                float* __restrict__ h,
                                                ushort* __restrict__ hb) {
    __shared__ float xs[64][IN_CH];
    int tid = threadIdx.x;
    int cx = tid & 31;
    int ny = tid >> 5;
    int nbase = blockIdx.x * 64;
    const float4* xg = (const float4*)(x + (size_t)nbase * IN_CH);
    float4* xs4 = (float4*)xs;
#pragma unroll
    for (int p = 0; p < 4; p++) {
        int i = p * 256 + tid;
        int row = i >> 4;
        xs4[i] = (nbase + row < NN) ? xg[i] : make_float4(0, 0, 0, 0);
    }
    __syncthreads();
    float4 acc[8];
#pragma unroll
    for (int j = 0; j < 8; j++) acc[j] = make_float4(0, 0, 0, 0);
    const float4* W4 = (const float4*)W;
#pragma unroll 4
    for (int k4 = 0; k4 < IN_CH / 4; k4++) {
        int k = 4 * k4;
        float4 w0 = W4[(k + 0) * 32 + cx];
        float4 w1 = W4[(k + 1) * 32 + cx];
        float4 w2 = W4[(k + 2) * 32 + cx];
        float4 w3 = W4[(k + 3) * 32 + cx];
#pragma unroll
        for (int j = 0; j < 8; j++) {
            float4 hv = *(const float4*)&xs[ny * 8 + j][k];
            acc[j].x += hv.x * w0.x + hv.y * w1.x + hv.z * w2.x + hv.w * w3.x;
            acc[j].y += hv.x * w0.y + hv.y * w1.y + hv.z * w2.y + hv.w * w3.y;
            acc[j].z += hv.x * w0.z + hv.y * w1.z + hv.z * w2.z + hv.w * w3.z;
            acc[j].w += hv.x * w0.w + hv.y * w1.w + hv.z * w2.w + hv.w * w3.w;
        }
    }
    float4 bc = ((const float4*)b)[cx];
    float4* mg = (float4*)h;
    ushort4* hbg = (ushort4*)hb;
#pragma unroll
    for (int j = 0; j < 8; j++) {
        int n = nbase + ny * 8 + j;
        if (n < NN) {
            float4 o;
            o.x = fmaxf(acc[j].x + bc.x, 0.f);
            o.y = fmaxf(acc[j].y + bc.y, 0.f);
            o.z = fmaxf(acc[j].z + bc.z, 0.f);
            o.w = fmaxf(acc[j].w + bc.w, 0.f);
            mg[n * 32 + cx] = o;
            ushort4 ob;
            ob.x = f2bf(o.x); ob.y = f2bf(o.y); ob.z = f2bf(o.z); ob.w = f2bf(o.w);
            hbg[n * 32 + cx] = ob;
        }
    }
}

// ---------------- per-layer GEMM via MFMA: m(bf16) = hb(bf16) @ W_l ----------------
__global__ __launch_bounds__(256) void k_gemm(const ushort* __restrict__ hb,
                                              const ushort* __restrict__ Wp,
                                              ushort* __restrict__ m) {
    int tid = threadIdx.x;
    int w = tid >> 6, l = tid & 63;
    int q = l >> 4, r16 = l & 15;
    int rowbase = blockIdx.x * 64 + w * 16;
    f4v acc[8];
#pragma unroll
    for (int t = 0; t < 8; t++) acc[t] = (f4v){0.f, 0.f, 0.f, 0.f};
    const s8v* wp = (const s8v*)Wp;
    int row = rowbase + r16;
#pragma unroll
    for (int kc = 0; kc < 4; kc++) {
        s8v afrag;
        if (row < NN) {
            afrag = *(const s8v*)(hb + (size_t)row * HID + kc * 32 + q * 8);
        } else {
            afrag = (s8v){0, 0, 0, 0, 0, 0, 0, 0};
        }
#pragma unroll
        for (int t = 0; t < 8; t++) {
            s8v bfrag = wp[(kc * 8 + t) * 64 + l];
            acc[t] = __builtin_amdgcn_mfma_f32_16x16x32_bf16(afrag, bfrag, acc[t], 0, 0, 0);
        }
    }
    // C/D layout: col = l&15, row = (l>>4)*4 + reg
#pragma unroll
    for (int t = 0; t < 8; t++) {
#pragma unroll
        for (int rg = 0; rg < 4; rg++) {
            int orow = rowbase + q * 4 + rg;
            if (orow < NN) m[(size_t)orow * HID + t * 16 + r16] = f2bf(acc[t][rg]);
        }
    }
}

// ---------------- aggregate + bias + LN + relu + residual (in-place h, + hb) ----------------
// one wave per node, 2 half-waves gather different edges' rows (uint2 = 4 bf16 ch/lane).
// 8 edges/iter from 2 broadcast uint4 record loads.  (round-8 proven form)
__global__ __launch_bounds__(256) void k_agg(const ushort* __restrict__ m,
                                             const int* __restrict__ rowp,
                                             const uint* __restrict__ erec,
                                             const float* __restrict__ dinv,
                                             const float* __restrict__ cb,
                                             const float* __restrict__ g,
                                             const float* __restrict__ bb,
                                             float* __restrict__ h,
                                             ushort* __restrict__ hb) {
    int lane = threadIdx.x & 63;
    int sub = lane & 31;           // channel quad: 4*sub..4*sub+3
    int hi = lane >> 5;            // which edge of the pair
    int n = blockIdx.x * 4 + (threadIdx.x >> 6);
    if (n >= NN) return;
    const uint2* mu2 = (const uint2*)m;
    float dn = dinv[n];
    float selfs = hi ? 0.0f : dn * dn;
    uint2 svu = mu2[(size_t)n * 32 + sub];
    float2 svl = bfu(svu.x), svh = bfu(svu.y);
    float4 a0, a1, a2, a3;
    a0.x = selfs * svl.x; a0.y = selfs * svl.y; a0.z = selfs * svh.x; a0.w = selfs * svh.y;
    a1 = make_float4(0, 0, 0, 0);
    a2 = make_float4(0, 0, 0, 0);
    a3 = make_float4(0, 0, 0, 0);
    int r0 = rowp[n], r1 = rowp[n + 1];          // multiples of 8
    const uint4* e4 = (const uint4*)erec;
    for (int r = r0; r < r1; r += 8) {
        int qb = r >> 2;
        uint4 rA = e4[qb + 0];                   // edges r .. r+3
        uint4 rB = e4[qb + 1];                   // edges r+4 .. r+7
        uint c0 = hi ? rA.y : rA.x;
        uint c1 = hi ? rA.w : rA.z;
        uint c2 = hi ? rB.y : rB.x;
        uint c3 = hi ? rB.w : rB.z;
        int s0 = c0 >> 15;  float v0 = (float)(c0 & 32767u) * (1.0f / VSCALE);
        int s1 = c1 >> 15;  float v1 = (float)(c1 & 32767u) * (1.0f / VSCALE);
        int s2 = c2 >> 15;  float v2 = (float)(c2 & 32767u) * (1.0f / VSCALE);
        int s3 = c3 >> 15;  float v3 = (float)(c3 & 32767u) * (1.0f / VSCALE);
        uint2 g0 = mu2[(size_t)s0 * 32 + sub];
        uint2 g1 = mu2[(size_t)s1 * 32 + sub];
        uint2 g2 = mu2[(size_t)s2 * 32 + sub];
        uint2 g3 = mu2[(size_t)s3 * 32 + sub];
        float2 f0l = bfu(g0.x), f0h = bfu(g0.y);
        float2 f1l = bfu(g1.x), f1h = bfu(g1.y);
        float2 f2l = bfu(g2.x), f2h = bfu(g2.y);
        float2 f3l = bfu(g3.x), f3h = bfu(g3.y);
        a0.x += v0 * f0l.x; a0.y += v0 * f0l.y; a0.z += v0 * f0h.x; a0.w += v0 * f0h.y;
        a1.x += v1 * f1l.x; a1.y += v1 * f1l.y; a1.z += v1 * f1h.x; a1.w += v1 * f1h.y;
        a2.x += v2 * f2l.x; a2.y += v2 * f2l.y; a2.z += v2 * f2h.x; a2.w += v2 * f2h.y;
        a3.x += v3 * f3l.x; a3.y += v3 * f3l.y; a3.z += v3 * f3h.x; a3.w += v3 * f3h.y;
    }
    float4 acc;
    acc.x = a0.x + a1.x + a2.x + a3.x;
    acc.y = a0.y + a1.y + a2.y + a3.y;
    acc.z = a0.z + a1.z + a2.z + a3.z;
    acc.w = a0.w + a1.w + a2.w + a3.w;
    // combine the two half-wave partial sums (lane l <-> l^32)
    acc.x += __shfl_xor(acc.x, 32, 64);
    acc.y += __shfl_xor(acc.y, 32, 64);
    acc.z += __shfl_xor(acc.z, 32, 64);
    acc.w += __shfl_xor(acc.w, 32, 64);
    float4 cbv = ((const float4*)cb)[sub];
    acc.x += cbv.x; acc.y += cbv.y; acc.z += cbv.z; acc.w += cbv.w;
    // LayerNorm over 128 channels: reduce across 32 lanes (both halves identical)
    float s1 = acc.x + acc.y + acc.z + acc.w;
    float s2 = acc.x * acc.x + acc.y * acc.y + acc.z * acc.z + acc.w * acc.w;
#pragma unroll
    for (int off = 16; off > 0; off >>= 1) {
        s1 += __shfl_down(s1, off, 32);
        s2 += __shfl_down(s2, off, 32);
    }
    s1 = __shfl(s1, 0, 32);
    s2 = __shfl(s2, 0, 32);
    float mu = s1 * (1.0f / HID);
    float var = s2 * (1.0f / HID) - mu * mu;
    float rs = rsqrtf(var + LN_EPS);
    if (hi == 0) {
        float4 gv = ((const float4*)g)[sub];
        float4 bv = ((const float4*)bb)[sub];
        float4* h4 = (float4*)h;
        float4 hv = h4[(size_t)n * 32 + sub];
        float4 o;
        o.x = fmaxf((acc.x - mu) * rs * gv.x + bv.x, 0.f) + hv.x;
        o.y = fmaxf((acc.y - mu) * rs * gv.y + bv.y, 0.f) + hv.y;
        o.z = fmaxf((acc.z - mu) * rs * gv.z + bv.z, 0.f) + hv.z;
        o.w = fmaxf((acc.w - mu) * rs * gv.w + bv.w, 0.f) + hv.w;
        h4[(size_t)n * 32 + sub] = o;
        ushort4 ob;
        ob.x = f2bf(o.x); ob.y = f2bf(o.y); ob.z = f2bf(o.z); ob.w = f2bf(o.w);
        ((ushort4*)hb)[(size_t)n * 32 + sub] = ob;
    }
}

// ---------------- launch ----------------

extern "C" void kernel_launch(void* const* d_in, const int* in_sizes, int n_in,
                              void* d_out, int out_size, void* d_ws, size_t ws_size,
                              hipStream_t stream) {
    const float* x    = (const float*)d_in[0];
    const int*   ei   = (const int*)d_in[1];
    const float* ew   = (const float*)d_in[2];
    const float* W_in = (const float*)d_in[3];
    const float* b_in = (const float*)d_in[4];
    const float* cW   = (const float*)d_in[5];
    const float* cb   = (const float*)d_in[6];
    const float* lg   = (const float*)d_in[7];
    const float* lb   = (const float*)d_in[8];
    float* h = (float*)d_out;

    char* ws = (char*)d_ws;
    unsigned long long* pk = (unsigned long long*)(ws + 0);   // 50000*64B padded (3.2 MB)
    int*    rowp     = (int*)   (ws + 3200000);               // 50001
    int*    rowp_tmp = (int*)   (ws + 3400064);
    int*    bsum     = (int*)   (ws + 3600064);               // 64
    int*    boff     = (int*)   (ws + 3600320);               // 64
    uint*   erec     = (uint*)  (ws + 3600576);               // ECAP u32 (4.6 MB)
    float*  dinv     = (float*) (ws + 8200576);               // 50000 f32
    ushort* Wp       = (ushort*)(ws + 8400576);               // 4*16384 bf16 (128 KB)
    ushort* m        = (ushort*)(ws + 8531648);               // 50000*128 bf16 (12.8 MB)
    int*    ord      = (int*)   (ws + 8531648);               // aliases m (dead until gemm)
    ushort* hb       = (ushort*)(ws + 21331648);              // 50000*128 bf16 (12.8 MB)

    const int NB = (NN + 1023) / 1024;                        // 49

    k_zero<<<(3200000 / 16 + 255) / 256, 256, 0, stream>>>((int4*)pk, 3200000 / 16);
    k_deg_cnt<<<(NE + 255) / 256, 256, 0, stream>>>(ei, ew, pk, ord);
    k_scan_a<<<NB, 1024, 0, stream>>>(pk, rowp_tmp, bsum, dinv);
    k_scan_b<<<1, 64, 0, stream>>>(bsum, boff, rowp, NB);
    k_scan_c<<<NB, 1024, 0, stream>>>(rowp_tmp, boff, pk, rowp, erec);
    k_scatter<<<(NE + 255) / 256, 256, 0, stream>>>(ei, ew, dinv, rowp, ord, erec);
    k_wpack<<<32, 256, 0, stream>>>(cW, Wp);

    k_inproj<<<(NN + 63) / 64, 256, 0, stream>>>(x, W_in, b_in, h, hb);

    for (int l = 0; l < NL; l++) {
        k_gemm<<<(NN + 63) / 64, 256, 0, stream>>>(hb, Wp + (size_t)l * 16384, m);
        k_agg<<<(NN + 3) / 4, 256, 0, stream>>>(m, rowp, erec, dinv,
                                                cb + l * HID, lg + l * HID, lb + l * HID, h, hb);
    }
}

// Round 13
// 311.771 us; speedup vs baseline: 1.0802x; 1.0792x over previous
//
#include <hip/hip_runtime.h>
#include <hip/hip_bf16.h>

#define NN 50000
#define NE 800000
#define IN_CH 64
#define HID 128
#define NL 4
#define LN_EPS 1e-5f

// padded CSR capacity: NE + 7*NN = 1,150,000
#define ECAP 1150000
#define WSCALE 1048576.0f   // 2^20 fixed point for edge-weight sums
#define VSCALE 32767.0f     // Q15 for packed edge values

typedef __attribute__((ext_vector_type(8))) short s8v;
typedef __attribute__((ext_vector_type(4))) float f4v;

__device__ inline ushort f2bf(float x) {
    __hip_bfloat16 h = __float2bfloat16(x);
    return *(ushort*)&h;
}
__device__ inline float2 bfu(uint u) {
    union { uint i; float f; } a, b;
    a.i = u << 16;
    b.i = u & 0xffff0000u;
    return make_float2(a.f, b.f);
}

// ---------------- preprocessing ----------------

__global__ void k_zero(int4* __restrict__ p, int n4) {
    int i = blockIdx.x * blockDim.x + threadIdx.x;
    if (i < n4) p[i] = make_int4(0, 0, 0, 0);
}

// one packed 64-bit atomic per edge: hi32 = count, lo32 = Q20 weight sum.
// unpadded pk: ~8 nodes/64B line amortizes one line over ~128 atomics (r12 lesson).
__global__ void k_deg_cnt(const int* __restrict__ ei, const float* __restrict__ ew,
                          unsigned long long* __restrict__ pk, int* __restrict__ ord) {
    int e = blockIdx.x * blockDim.x + threadIdx.x;
    if (e >= NE) return;
    int d = ei[NE + e];
    unsigned int wq = (unsigned int)__float2uint_rn(ew[e] * WSCALE);
    unsigned long long old = atomicAdd(&pk[d], (1ULL << 32) | (unsigned long long)wq);
    ord[e] = (int)(old >> 32);
}

// hierarchical scan of padded counts ((cnt+7)&~7) -> rowp (exclusive); fused dinv
__global__ __launch_bounds__(1024) void k_scan_a(const unsigned long long* __restrict__ pk,
                                                 int* __restrict__ rowp_tmp,
                                                 int* __restrict__ bsum,
                                                 float* __restrict__ dinv) {
    __shared__ int wsum[16];
    int tid = threadIdx.x;
    int lane = tid & 63, wv = tid >> 6;
    int i = blockIdx.x * 1024 + tid;
    unsigned long long pv = (i < NN) ? pk[i] : 0ULL;
    if (i < NN) {
        float deg = (float)(unsigned int)(pv & 0xffffffffu) * (1.0f / WSCALE);
        dinv[i] = rsqrtf(deg + 1.0f);
    }
    int v = (((int)(pv >> 32) + 7) & ~7);
    int s = v;
#pragma unroll
    for (int off = 1; off < 64; off <<= 1) {
        int t = __shfl_up(s, off, 64);
        if (lane >= off) s += t;
    }
    if (lane == 63) wsum[wv] = s;
    __syncthreads();
    int woff = 0;
    for (int w = 0; w < wv; w++) woff += wsum[w];
    if (i < NN) rowp_tmp[i] = woff + s - v;
    if (tid == 1023) bsum[blockIdx.x] = woff + s;
}

__global__ __launch_bounds__(64) void k_scan_b(const int* __restrict__ bsum,
                                               int* __restrict__ boff,
                                               int* __restrict__ rowp, int nb) {
    int t = threadIdx.x;
    int v = (t < nb) ? bsum[t] : 0;
    int s = v;
#pragma unroll
    for (int off = 1; off < 64; off <<= 1) {
        int u = __shfl_up(s, off, 64);
        if (t >= off) s += u;
    }
    if (t < nb) boff[t] = s - v;
    if (t == 63) rowp[NN] = s;
}

// phase c: finalize rowp AND zero the padding slots (fused k_pad)
__global__ __launch_bounds__(1024) void k_scan_c(const int* __restrict__ rowp_tmp,
                                                 const int* __restrict__ boff,
                                                 const unsigned long long* __restrict__ pk,
                                                 int* __restrict__ rowp,
                                                 uint* __restrict__ erec) {
    int i = blockIdx.x * 1024 + threadIdx.x;
    if (i >= NN) return;
    int start = rowp_tmp[i] + boff[blockIdx.x];
    rowp[i] = start;
    int cnt = (int)(pk[i] >> 32);
    int v = (cnt + 7) & ~7;
    for (int p = start + cnt; p < start + v; p++) erec[p] = 0u;
}

// atomic-free scatter: pos = rowp[d] + ord[e]; one u32 record (src<<15 | Q15 val)
__global__ void k_scatter(const int* __restrict__ ei, const float* __restrict__ ew,
                          const float* __restrict__ dinv, const int* __restrict__ rowp,
                          const int* __restrict__ ord, uint* __restrict__ erec) {
    int e = blockIdx.x * blockDim.x + threadIdx.x;
    if (e >= NE) return;
    int s = ei[e];
    int d = ei[NE + e];
    int pos = rowp[d] + ord[e];
    float v = dinv[s] * ew[e] * dinv[d];               // in (0, 1]
    uint q = (uint)__float2int_rn(v * VSCALE);
    erec[pos] = ((uint)s << 15) | q;
}

// ---------------- W repack for MFMA: all layers at once ----------------
__global__ __launch_bounds__(256) void k_wpack(const float* __restrict__ cW,
                                               ushort* __restrict__ Wp) {
    int gid = blockIdx.x * 256 + threadIdx.x;          // 0 .. 8191
    int lane = gid & 63;
    int t = (gid >> 6) & 7;
    int kc = (gid >> 9) & 3;
    int layer = gid >> 11;
    const float* W = cW + (size_t)layer * HID * HID;
    int kbase = kc * 32 + (lane >> 4) * 8;
    int col = t * 16 + (lane & 15);
    ushort o[8];
#pragma unroll
    for (int j = 0; j < 8; j++) o[j] = f2bf(W[(size_t)(kbase + j) * HID + col]);
    uint4 pk4;
    pk4.x = (uint)o[0] | ((uint)o[1] << 16);
    pk4.y = (uint)o[2] | ((uint)o[3] << 16);
    pk4.z = (uint)o[4] | ((uint)o[5] << 16);
    pk4.w = (uint)o[6] | ((uint)o[7] << 16);
    ((uint4*)Wp)[gid] = pk4;
}

// ---------------- input projection: h = relu(x @ W_in + b_in); also hb (bf16) ----------------
__global__ __launch_bounds__(256) void k_inproj(const float* __restrict__ x,
                                                const float* __restrict__ W,
                                                const float* __restrict__ b,
                                                float* __restrict__ h,
                                                ushort* __restrict__ hb) {
    __shared__ float xs[64][IN_CH];
    int tid = threadIdx.x;
    int cx = tid & 31;
    int ny = tid >> 5;
    int nbase = blockIdx.x * 64;
    const float4* xg = (const float4*)(x + (size_t)nbase * IN_CH);
    float4* xs4 = (float4*)xs;
#pragma unroll
    for (int p = 0; p < 4; p++) {
        int i = p * 256 + tid;
        int row = i >> 4;
        xs4[i] = (nbase + row < NN) ? xg[i] : make_float4(0, 0, 0, 0);
    }
    __syncthreads();
    float4 acc[8];
#pragma unroll
    for (int j = 0; j < 8; j++) acc[j] = make_float4(0, 0, 0, 0);
    const float4* W4 = (const float4*)W;
#pragma unroll 4
    for (int k4 = 0; k4 < IN_CH / 4; k4++) {
        int k = 4 * k4;
        float4 w0 = W4[(k + 0) * 32 + cx];
        float4 w1 = W4[(k + 1) * 32 + cx];
        float4 w2 = W4[(k + 2) * 32 + cx];
        float4 w3 = W4[(k + 3) * 32 + cx];
#pragma unroll
        for (int j = 0; j < 8; j++) {
            float4 hv = *(const float4*)&xs[ny * 8 + j][k];
            acc[j].x += hv.x * w0.x + hv.y * w1.x + hv.z * w2.x + hv.w * w3.x;
            acc[j].y += hv.x * w0.y + hv.y * w1.y + hv.z * w2.y + hv.w * w3.y;
            acc[j].z += hv.x * w0.z + hv.y * w1.z + hv.z * w2.z + hv.w * w3.z;
            acc[j].w += hv.x * w0.w + hv.y * w1.w + hv.z * w2.w + hv.w * w3.w;
        }
    }
    float4 bc = ((const float4*)b)[cx];
    float4* mg = (float4*)h;
    ushort4* hbg = (ushort4*)hb;
#pragma unroll
    for (int j = 0; j < 8; j++) {
        int n = nbase + ny * 8 + j;
        if (n < NN) {
            float4 o;
            o.x = fmaxf(acc[j].x + bc.x, 0.f);
            o.y = fmaxf(acc[j].y + bc.y, 0.f);
            o.z = fmaxf(acc[j].z + bc.z, 0.f);
            o.w = fmaxf(acc[j].w + bc.w, 0.f);
            mg[n * 32 + cx] = o;
            ushort4 ob;
            ob.x = f2bf(o.x); ob.y = f2bf(o.y); ob.z = f2bf(o.z); ob.w = f2bf(o.w);
            hbg[n * 32 + cx] = ob;
        }
    }
}

// ---------------- per-layer GEMM via MFMA: m(bf16) = hb(bf16) @ W_l ----------------
__global__ __launch_bounds__(256) void k_gemm(const ushort* __restrict__ hb,
                                              const ushort* __restrict__ Wp,
                                              ushort* __restrict__ m) {
    int tid = threadIdx.x;
    int w = tid >> 6, l = tid & 63;
    int q = l >> 4, r16 = l & 15;
    int rowbase = blockIdx.x * 64 + w * 16;
    f4v acc[8];
#pragma unroll
    for (int t = 0; t < 8; t++) acc[t] = (f4v){0.f, 0.f, 0.f, 0.f};
    const s8v* wp = (const s8v*)Wp;
    int row = rowbase + r16;
#pragma unroll
    for (int kc = 0; kc < 4; kc++) {
        s8v afrag;
        if (row < NN) {
            afrag = *(const s8v*)(hb + (size_t)row * HID + kc * 32 + q * 8);
        } else {
            afrag = (s8v){0, 0, 0, 0, 0, 0, 0, 0};
        }
#pragma unroll
        for (int t = 0; t < 8; t++) {
            s8v bfrag = wp[(kc * 8 + t) * 64 + l];
            acc[t] = __builtin_amdgcn_mfma_f32_16x16x32_bf16(afrag, bfrag, acc[t], 0, 0, 0);
        }
    }
    // C/D layout: col = l&15, row = (l>>4)*4 + reg
#pragma unroll
    for (int t = 0; t < 8; t++) {
#pragma unroll
        for (int rg = 0; rg < 4; rg++) {
            int orow = rowbase + q * 4 + rg;
            if (orow < NN) m[(size_t)orow * HID + t * 16 + r16] = f2bf(acc[t][rg]);
        }
    }
}

// ---------------- aggregate + bias + LN + relu + residual (in-place h, + hb) ----------------
// one wave per node, 2 half-waves gather different edges' rows (uint2 = 4 bf16 ch/lane).
// 8 edges/iter from 2 broadcast uint4 record loads.  (round-8 proven form)
__global__ __launch_bounds__(256) void k_agg(const ushort* __restrict__ m,
                                             const int* __restrict__ rowp,
                                             const uint* __restrict__ erec,
                                             const float* __restrict__ dinv,
                                             const float* __restrict__ cb,
                                             const float* __restrict__ g,
                                             const float* __restrict__ bb,
                                             float* __restrict__ h,
                                             ushort* __restrict__ hb) {
    int lane = threadIdx.x & 63;
    int sub = lane & 31;           // channel quad: 4*sub..4*sub+3
    int hi = lane >> 5;            // which edge of the pair
    int n = blockIdx.x * 4 + (threadIdx.x >> 6);
    if (n >= NN) return;
    const uint2* mu2 = (const uint2*)m;
    float dn = dinv[n];
    float selfs = hi ? 0.0f : dn * dn;
    uint2 svu = mu2[(size_t)n * 32 + sub];
    float2 svl = bfu(svu.x), svh = bfu(svu.y);
    float4 a0, a1, a2, a3;
    a0.x = selfs * svl.x; a0.y = selfs * svl.y; a0.z = selfs * svh.x; a0.w = selfs * svh.y;
    a1 = make_float4(0, 0, 0, 0);
    a2 = make_float4(0, 0, 0, 0);
    a3 = make_float4(0, 0, 0, 0);
    int r0 = rowp[n], r1 = rowp[n + 1];          // multiples of 8
    const uint4* e4 = (const uint4*)erec;
    for (int r = r0; r < r1; r += 8) {
        int qb = r >> 2;
        uint4 rA = e4[qb + 0];                   // edges r .. r+3
        uint4 rB = e4[qb + 1];                   // edges r+4 .. r+7
        uint c0 = hi ? rA.y : rA.x;
        uint c1 = hi ? rA.w : rA.z;
        uint c2 = hi ? rB.y : rB.x;
        uint c3 = hi ? rB.w : rB.z;
        int s0 = c0 >> 15;  float v0 = (float)(c0 & 32767u) * (1.0f / VSCALE);
        int s1 = c1 >> 15;  float v1 = (float)(c1 & 32767u) * (1.0f / VSCALE);
        int s2 = c2 >> 15;  float v2 = (float)(c2 & 32767u) * (1.0f / VSCALE);
        int s3 = c3 >> 15;  float v3 = (float)(c3 & 32767u) * (1.0f / VSCALE);
        uint2 g0 = mu2[(size_t)s0 * 32 + sub];
        uint2 g1 = mu2[(size_t)s1 * 32 + sub];
        uint2 g2 = mu2[(size_t)s2 * 32 + sub];
        uint2 g3 = mu2[(size_t)s3 * 32 + sub];
        float2 f0l = bfu(g0.x), f0h = bfu(g0.y);
        float2 f1l = bfu(g1.x), f1h = bfu(g1.y);
        float2 f2l = bfu(g2.x), f2h = bfu(g2.y);
        float2 f3l = bfu(g3.x), f3h = bfu(g3.y);
        a0.x += v0 * f0l.x; a0.y += v0 * f0l.y; a0.z += v0 * f0h.x; a0.w += v0 * f0h.y;
        a1.x += v1 * f1l.x; a1.y += v1 * f1l.y; a1.z += v1 * f1h.x; a1.w += v1 * f1h.y;
        a2.x += v2 * f2l.x; a2.y += v2 * f2l.y; a2.z += v2 * f2h.x; a2.w += v2 * f2h.y;
        a3.x += v3 * f3l.x; a3.y += v3 * f3l.y; a3.z += v3 * f3h.x; a3.w += v3 * f3h.y;
    }
    float4 acc;
    acc.x = a0.x + a1.x + a2.x + a3.x;
    acc.y = a0.y + a1.y + a2.y + a3.y;
    acc.z = a0.z + a1.z + a2.z + a3.z;
    acc.w = a0.w + a1.w + a2.w + a3.w;
    // combine the two half-wave partial sums (lane l <-> l^32)
    acc.x += __shfl_xor(acc.x, 32, 64);
    acc.y += __shfl_xor(acc.y, 32, 64);
    acc.z += __shfl_xor(acc.z, 32, 64);
    acc.w += __shfl_xor(acc.w, 32, 64);
    float4 cbv = ((const float4*)cb)[sub];
    acc.x += cbv.x; acc.y += cbv.y; acc.z += cbv.z; acc.w += cbv.w;
    // LayerNorm over 128 channels: reduce across 32 lanes (both halves identical)
    float s1 = acc.x + acc.y + acc.z + acc.w;
    float s2 = acc.x * acc.x + acc.y * acc.y + acc.z * acc.z + acc.w * acc.w;
#pragma unroll
    for (int off = 16; off > 0; off >>= 1) {
        s1 += __shfl_down(s1, off, 32);
        s2 += __shfl_down(s2, off, 32);
    }
    s1 = __shfl(s1, 0, 32);
    s2 = __shfl(s2, 0, 32);
    float mu = s1 * (1.0f / HID);
    float var = s2 * (1.0f / HID) - mu * mu;
    float rs = rsqrtf(var + LN_EPS);
    if (hi == 0) {
        float4 gv = ((const float4*)g)[sub];
        float4 bv = ((const float4*)bb)[sub];
        float4* h4 = (float4*)h;
        float4 hv = h4[(size_t)n * 32 + sub];
        float4 o;
        o.x = fmaxf((acc.x - mu) * rs * gv.x + bv.x, 0.f) + hv.x;
        o.y = fmaxf((acc.y - mu) * rs * gv.y + bv.y, 0.f) + hv.y;
        o.z = fmaxf((acc.z - mu) * rs * gv.z + bv.z, 0.f) + hv.z;
        o.w = fmaxf((acc.w - mu) * rs * gv.w + bv.w, 0.f) + hv.w;
        h4[(size_t)n * 32 + sub] = o;
        ushort4 ob;
        ob.x = f2bf(o.x); ob.y = f2bf(o.y); ob.z = f2bf(o.z); ob.w = f2bf(o.w);
        ((ushort4*)hb)[(size_t)n * 32 + sub] = ob;
    }
}

// ---------------- launch ----------------

extern "C" void kernel_launch(void* const* d_in, const int* in_sizes, int n_in,
                              void* d_out, int out_size, void* d_ws, size_t ws_size,
                              hipStream_t stream) {
    const float* x    = (const float*)d_in[0];
    const int*   ei   = (const int*)d_in[1];
    const float* ew   = (const float*)d_in[2];
    const float* W_in = (const float*)d_in[3];
    const float* b_in = (const float*)d_in[4];
    const float* cW   = (const float*)d_in[5];
    const float* cb   = (const float*)d_in[6];
    const float* lg   = (const float*)d_in[7];
    const float* lb   = (const float*)d_in[8];
    float* h = (float*)d_out;

    char* ws = (char*)d_ws;
    unsigned long long* pk = (unsigned long long*)(ws + 0);   // 50000 u64 (400 KB)
    int*    rowp     = (int*)   (ws + 401408);                // 50001
    int*    rowp_tmp = (int*)   (ws + 602112);
    int*    bsum     = (int*)   (ws + 802816);                // 64
    int*    boff     = (int*)   (ws + 803072);                // 64
    uint*   erec     = (uint*)  (ws + 803328);                // ECAP u32 (4.6 MB)
    float*  dinv     = (float*) (ws + 5403328);               // 50000 f32
    ushort* Wp       = (ushort*)(ws + 5603328);               // 4*16384 bf16 (128 KB)
    ushort* m        = (ushort*)(ws + 5734400);               // 50000*128 bf16 (12.8 MB)
    int*    ord      = (int*)   (ws + 5734400);               // aliases m (dead until gemm)
    ushort* hb       = (ushort*)(ws + 18534400);              // 50000*128 bf16 (12.8 MB)

    const int NB = (NN + 1023) / 1024;                        // 49

    k_zero<<<(100000 / 4 + 255) / 256, 256, 0, stream>>>((int4*)pk, 100000 / 4);
    k_deg_cnt<<<(NE + 255) / 256, 256, 0, stream>>>(ei, ew, pk, ord);
    k_scan_a<<<NB, 1024, 0, stream>>>(pk, rowp_tmp, bsum, dinv);
    k_scan_b<<<1, 64, 0, stream>>>(bsum, boff, rowp, NB);
    k_scan_c<<<NB, 1024, 0, stream>>>(rowp_tmp, boff, pk, rowp, erec);
    k_scatter<<<(NE + 255) / 256, 256, 0, stream>>>(ei, ew, dinv, rowp, ord, erec);
    k_wpack<<<32, 256, 0, stream>>>(cW, Wp);

    k_inproj<<<(NN + 63) / 64, 256, 0, stream>>>(x, W_in, b_in, h, hb);

    for (int l = 0; l < NL; l++) {
        k_gemm<<<(NN + 63) / 64, 256, 0, stream>>>(hb, Wp + (size_t)l * 16384, m);
        k_agg<<<(NN + 3) / 4, 256, 0, stream>>>(m, rowp, erec, dinv,
                                                cb + l * HID, lg + l * HID, lb + l * HID, h, hb);
    }
}

// Round 14
// 285.714 us; speedup vs baseline: 1.1787x; 1.0912x over previous
//
#include <hip/hip_runtime.h>
#include <hip/hip_bf16.h>

#define NN 50000
#define NE 800000
#define IN_CH 64
#define HID 128
#define NL 4
#define LN_EPS 1e-5f

// padded CSR capacity: NE + 7*NN = 1,150,000
#define ECAP 1150000
#define WSCALE 1048576.0f   // 2^20 fixed point for edge-weight sums
#define VSCALE 32767.0f     // Q15 for packed edge values

typedef __attribute__((ext_vector_type(8))) short s8v;
typedef __attribute__((ext_vector_type(4))) float f4v;

__device__ inline ushort f2bf(float x) {
    __hip_bfloat16 h = __float2bfloat16(x);
    return *(ushort*)&h;
}
__device__ inline float4 i8u(uint u) {
    float4 r;
    r.x = (float)(int)(signed char)(u & 0xffu);
    r.y = (float)(int)(signed char)((u >> 8) & 0xffu);
    r.z = (float)(int)(signed char)((u >> 16) & 0xffu);
    r.w = (float)(int)(signed char)(u >> 24);
    return r;
}

// ---------------- preprocessing ----------------

__global__ void k_zero(int4* __restrict__ p, int n4) {
    int i = blockIdx.x * blockDim.x + threadIdx.x;
    if (i < n4) p[i] = make_int4(0, 0, 0, 0);
}

// one packed 64-bit atomic per edge: hi32 = count, lo32 = Q20 weight sum.
// unpadded pk: ~8 nodes/64B line amortizes one line over ~128 atomics (r12 lesson).
__global__ void k_deg_cnt(const int* __restrict__ ei, const float* __restrict__ ew,
                          unsigned long long* __restrict__ pk, int* __restrict__ ord) {
    int e = blockIdx.x * blockDim.x + threadIdx.x;
    if (e >= NE) return;
    int d = ei[NE + e];
    unsigned int wq = (unsigned int)__float2uint_rn(ew[e] * WSCALE);
    unsigned long long old = atomicAdd(&pk[d], (1ULL << 32) | (unsigned long long)wq);
    ord[e] = (int)(old >> 32);
}

// hierarchical scan of padded counts ((cnt+7)&~7) -> rowp (exclusive); fused dinv
__global__ __launch_bounds__(1024) void k_scan_a(const unsigned long long* __restrict__ pk,
                                                 int* __restrict__ rowp_tmp,
                                                 int* __restrict__ bsum,
                                                 float* __restrict__ dinv) {
    __shared__ int wsum[16];
    int tid = threadIdx.x;
    int lane = tid & 63, wv = tid >> 6;
    int i = blockIdx.x * 1024 + tid;
    unsigned long long pv = (i < NN) ? pk[i] : 0ULL;
    if (i < NN) {
        float deg = (float)(unsigned int)(pv & 0xffffffffu) * (1.0f / WSCALE);
        dinv[i] = rsqrtf(deg + 1.0f);
    }
    int v = (((int)(pv >> 32) + 7) & ~7);
    int s = v;
#pragma unroll
    for (int off = 1; off < 64; off <<= 1) {
        int t = __shfl_up(s, off, 64);
        if (lane >= off) s += t;
    }
    if (lane == 63) wsum[wv] = s;
    __syncthreads();
    int woff = 0;
    for (int w = 0; w < wv; w++) woff += wsum[w];
    if (i < NN) rowp_tmp[i] = woff + s - v;
    if (tid == 1023) bsum[blockIdx.x] = woff + s;
}

__global__ __launch_bounds__(64) void k_scan_b(const int* __restrict__ bsum,
                                               int* __restrict__ boff,
                                               int* __restrict__ rowp, int nb) {
    int t = threadIdx.x;
    int v = (t < nb) ? bsum[t] : 0;
    int s = v;
#pragma unroll
    for (int off = 1; off < 64; off <<= 1) {
        int u = __shfl_up(s, off, 64);
        if (t >= off) s += u;
    }
    if (t < nb) boff[t] = s - v;
    if (t == 63) rowp[NN] = s;
}

// phase c: finalize rowp AND zero the padding slots (fused k_pad)
__global__ __launch_bounds__(1024) void k_scan_c(const int* __restrict__ rowp_tmp,
                                                 const int* __restrict__ boff,
                                                 const unsigned long long* __restrict__ pk,
                                                 int* __restrict__ rowp,
                                                 uint* __restrict__ erec) {
    int i = blockIdx.x * 1024 + threadIdx.x;
    if (i >= NN) return;
    int start = rowp_tmp[i] + boff[blockIdx.x];
    rowp[i] = start;
    int cnt = (int)(pk[i] >> 32);
    int v = (cnt + 7) & ~7;
    for (int p = start + cnt; p < start + v; p++) erec[p] = 0u;
}

// atomic-free scatter: pos = rowp[d] + ord[e]; one u32 record (src<<15 | Q15 val)
__global__ void k_scatter(const int* __restrict__ ei, const float* __restrict__ ew,
                          const float* __restrict__ dinv, const int* __restrict__ rowp,
                          const int* __restrict__ ord, uint* __restrict__ erec) {
    int e = blockIdx.x * blockDim.x + threadIdx.x;
    if (e >= NE) return;
    int s = ei[e];
    int d = ei[NE + e];
    int pos = rowp[d] + ord[e];
    float v = dinv[s] * ew[e] * dinv[d];               // in (0, 1]
    uint q = (uint)__float2int_rn(v * VSCALE);
    erec[pos] = ((uint)s << 15) | q;
}

// ---------------- W repack for MFMA: all layers at once ----------------
__global__ __launch_bounds__(256) void k_wpack(const float* __restrict__ cW,
                                               ushort* __restrict__ Wp) {
    int gid = blockIdx.x * 256 + threadIdx.x;          // 0 .. 8191
    int lane = gid & 63;
    int t = (gid >> 6) & 7;
    int kc = (gid >> 9) & 3;
    int layer = gid >> 11;
    const float* W = cW + (size_t)layer * HID * HID;
    int kbase = kc * 32 + (lane >> 4) * 8;
    int col = t * 16 + (lane & 15);
    ushort o[8];
#pragma unroll
    for (int j = 0; j < 8; j++) o[j] = f2bf(W[(size_t)(kbase + j) * HID + col]);
    uint4 pk4;
    pk4.x = (uint)o[0] | ((uint)o[1] << 16);
    pk4.y = (uint)o[2] | ((uint)o[3] << 16);
    pk4.z = (uint)o[4] | ((uint)o[5] << 16);
    pk4.w = (uint)o[6] | ((uint)o[7] << 16);
    ((uint4*)Wp)[gid] = pk4;
}

// ---------------- input projection: h = relu(x @ W_in + b_in); also hb (bf16) ----------------
__global__ __launch_bounds__(256) void k_inproj(const float* __restrict__ x,
                                                const float* __restrict__ W,
                                                const float* __restrict__ b,
                                                float* __restrict__ h,
                                                ushort* __restrict__ hb) {
    __shared__ float xs[64][IN_CH];
    int tid = threadIdx.x;
    int cx = tid & 31;
    int ny = tid >> 5;
    int nbase = blockIdx.x * 64;
    const float4* xg = (const float4*)(x + (size_t)nbase * IN_CH);
    float4* xs4 = (float4*)xs;
#pragma unroll
    for (int p = 0; p < 4; p++) {
        int i = p * 256 + tid;
        int row = i >> 4;
        xs4[i] = (nbase + row < NN) ? xg[i] : make_float4(0, 0, 0, 0);
    }
    __syncthreads();
    float4 acc[8];
#pragma unroll
    for (int j = 0; j < 8; j++) acc[j] = make_float4(0, 0, 0, 0);
    const float4* W4 = (const float4*)W;
#pragma unroll 4
    for (int k4 = 0; k4 < IN_CH / 4; k4++) {
        int k = 4 * k4;
        float4 w0 = W4[(k + 0) * 32 + cx];
        float4 w1 = W4[(k + 1) * 32 + cx];
        float4 w2 = W4[(k + 2) * 32 + cx];
        float4 w3 = W4[(k + 3) * 32 + cx];
#pragma unroll
        for (int j = 0; j < 8; j++) {
            float4 hv = *(const float4*)&xs[ny * 8 + j][k];
            acc[j].x += hv.x * w0.x + hv.y * w1.x + hv.z * w2.x + hv.w * w3.x;
            acc[j].y += hv.x * w0.y + hv.y * w1.y + hv.z * w2.y + hv.w * w3.y;
            acc[j].z += hv.x * w0.z + hv.y * w1.z + hv.z * w2.z + hv.w * w3.z;
            acc[j].w += hv.x * w0.w + hv.y * w1.w + hv.z * w2.w + hv.w * w3.w;
        }
    }
    float4 bc = ((const float4*)b)[cx];
    float4* mg = (float4*)h;
    ushort4* hbg = (ushort4*)hb;
#pragma unroll
    for (int j = 0; j < 8; j++) {
        int n = nbase + ny * 8 + j;
        if (n < NN) {
            float4 o;
            o.x = fmaxf(acc[j].x + bc.x, 0.f);
            o.y = fmaxf(acc[j].y + bc.y, 0.f);
            o.z = fmaxf(acc[j].z + bc.z, 0.f);
            o.w = fmaxf(acc[j].w + bc.w, 0.f);
            mg[n * 32 + cx] = o;
            ushort4 ob;
            ob.x = f2bf(o.x); ob.y = f2bf(o.y); ob.z = f2bf(o.z); ob.w = f2bf(o.w);
            hbg[n * 32 + cx] = ob;
        }
    }
}

// ---------------- per-layer GEMM via MFMA: m8(int8, per-row scale) = hb @ W_l ----------------
__global__ __launch_bounds__(256) void k_gemm(const ushort* __restrict__ hb,
                                              const ushort* __restrict__ Wp,
                                              signed char* __restrict__ m8,
                                              float* __restrict__ sc) {
    int tid = threadIdx.x;
    int w = tid >> 6, l = tid & 63;
    int q = l >> 4, r16 = l & 15;
    int rowbase = blockIdx.x * 64 + w * 16;
    f4v acc[8];
#pragma unroll
    for (int t = 0; t < 8; t++) acc[t] = (f4v){0.f, 0.f, 0.f, 0.f};
    const s8v* wp = (const s8v*)Wp;
    int row = rowbase + r16;
#pragma unroll
    for (int kc = 0; kc < 4; kc++) {
        s8v afrag;
        if (row < NN) {
            afrag = *(const s8v*)(hb + (size_t)row * HID + kc * 32 + q * 8);
        } else {
            afrag = (s8v){0, 0, 0, 0, 0, 0, 0, 0};
        }
#pragma unroll
        for (int t = 0; t < 8; t++) {
            s8v bfrag = wp[(kc * 8 + t) * 64 + l];
            acc[t] = __builtin_amdgcn_mfma_f32_16x16x32_bf16(afrag, bfrag, acc[t], 0, 0, 0);
        }
    }
    // C/D layout: col = l&15, row = (l>>4)*4 + reg.
    // Per output row: |max| over 8 regs + 16-lane reduce -> int8 quant + scale.
#pragma unroll
    for (int rg = 0; rg < 4; rg++) {
        float rmax = 0.f;
#pragma unroll
        for (int t = 0; t < 8; t++) rmax = fmaxf(rmax, fabsf(acc[t][rg]));
#pragma unroll
        for (int off = 1; off < 16; off <<= 1)
            rmax = fmaxf(rmax, __shfl_xor(rmax, off, 16));
        rmax = fmaxf(rmax, 1e-20f);
        float scale = rmax * (1.0f / 127.0f);
        float inv = 127.0f / rmax;
        int orow = rowbase + q * 4 + rg;
        if (orow < NN) {
#pragma unroll
            for (int t = 0; t < 8; t++) {
                int qi = __float2int_rn(acc[t][rg] * inv);
                m8[(size_t)orow * HID + t * 16 + r16] = (signed char)qi;
            }
            if (r16 == 0) sc[orow] = scale;
        }
    }
}

// ---------------- aggregate + bias + LN + relu + residual (in-place h, + hb) ----------------
// one wave per node, 2 half-waves gather different edges' rows (uint = 4 int8 ch/lane).
// 8 edges/iter from 2 broadcast uint4 record loads.  (r8 structure, int8 rows)
__global__ __launch_bounds__(256) void k_agg(const signed char* __restrict__ m8,
                                             const float* __restrict__ sc,
                                             const int* __restrict__ rowp,
                                             const uint* __restrict__ erec,
                                             const float* __restrict__ dinv,
                                             const float* __restrict__ cb,
                                             const float* __restrict__ g,
                                             const float* __restrict__ bb,
                                             float* __restrict__ h,
                                             ushort* __restrict__ hb) {
    int lane = threadIdx.x & 63;
    int sub = lane & 31;           // channel quad: 4*sub..4*sub+3
    int hi = lane >> 5;            // which edge of the pair
    int n = blockIdx.x * 4 + (threadIdx.x >> 6);
    if (n >= NN) return;
    const uint* mu = (const uint*)m8;
    float dn = dinv[n];
    float selfs = hi ? 0.0f : dn * dn * sc[n];
    float4 sv = i8u(mu[(size_t)n * 32 + sub]);
    float4 a0, a1, a2, a3;
    a0.x = selfs * sv.x; a0.y = selfs * sv.y; a0.z = selfs * sv.z; a0.w = selfs * sv.w;
    a1 = make_float4(0, 0, 0, 0);
    a2 = make_float4(0, 0, 0, 0);
    a3 = make_float4(0, 0, 0, 0);
    int r0 = rowp[n], r1 = rowp[n + 1];          // multiples of 8
    const uint4* e4 = (const uint4*)erec;
    for (int r = r0; r < r1; r += 8) {
        int qb = r >> 2;
        uint4 rA = e4[qb + 0];                   // edges r .. r+3
        uint4 rB = e4[qb + 1];                   // edges r+4 .. r+7
        uint c0 = hi ? rA.y : rA.x;
        uint c1 = hi ? rA.w : rA.z;
        uint c2 = hi ? rB.y : rB.x;
        uint c3 = hi ? rB.w : rB.z;
        int s0 = c0 >> 15;  int s1 = c1 >> 15;
        int s2 = c2 >> 15;  int s3 = c3 >> 15;
        float v0 = (float)(c0 & 32767u) * (1.0f / VSCALE) * sc[s0];
        float v1 = (float)(c1 & 32767u) * (1.0f / VSCALE) * sc[s1];
        float v2 = (float)(c2 & 32767u) * (1.0f / VSCALE) * sc[s2];
        float v3 = (float)(c3 & 32767u) * (1.0f / VSCALE) * sc[s3];
        float4 f0 = i8u(mu[(size_t)s0 * 32 + sub]);
        float4 f1 = i8u(mu[(size_t)s1 * 32 + sub]);
        float4 f2 = i8u(mu[(size_t)s2 * 32 + sub]);
        float4 f3 = i8u(mu[(size_t)s3 * 32 + sub]);
        a0.x += v0 * f0.x; a0.y += v0 * f0.y; a0.z += v0 * f0.z; a0.w += v0 * f0.w;
        a1.x += v1 * f1.x; a1.y += v1 * f1.y; a1.z += v1 * f1.z; a1.w += v1 * f1.w;
        a2.x += v2 * f2.x; a2.y += v2 * f2.y; a2.z += v2 * f2.z; a2.w += v2 * f2.w;
        a3.x += v3 * f3.x; a3.y += v3 * f3.y; a3.z += v3 * f3.z; a3.w += v3 * f3.w;
    }
    float4 acc;
    acc.x = a0.x + a1.x + a2.x + a3.x;
    acc.y = a0.y + a1.y + a2.y + a3.y;
    acc.z = a0.z + a1.z + a2.z + a3.z;
    acc.w = a0.w + a1.w + a2.w + a3.w;
    // combine the two half-wave partial sums (lane l <-> l^32)
    acc.x += __shfl_xor(acc.x, 32, 64);
    acc.y += __shfl_xor(acc.y, 32, 64);
    acc.z += __shfl_xor(acc.z, 32, 64);
    acc.w += __shfl_xor(acc.w, 32, 64);
    float4 cbv = ((const float4*)cb)[sub];
    acc.x += cbv.x; acc.y += cbv.y; acc.z += cbv.z; acc.w += cbv.w;
    // LayerNorm over 128 channels: reduce across 32 lanes (both halves identical)
    float s1 = acc.x + acc.y + acc.z + acc.w;
    float s2 = acc.x * acc.x + acc.y * acc.y + acc.z * acc.z + acc.w * acc.w;
#pragma unroll
    for (int off = 16; off > 0; off >>= 1) {
        s1 += __shfl_down(s1, off, 32);
        s2 += __shfl_down(s2, off, 32);
    }
    s1 = __shfl(s1, 0, 32);
    s2 = __shfl(s2, 0, 32);
    float mu_ = s1 * (1.0f / HID);
    float var = s2 * (1.0f / HID) - mu_ * mu_;
    float rs = rsqrtf(var + LN_EPS);
    if (hi == 0) {
        float4 gv = ((const float4*)g)[sub];
        float4 bv = ((const float4*)bb)[sub];
        float4* h4 = (float4*)h;
        float4 hv = h4[(size_t)n * 32 + sub];
        float4 o;
        o.x = fmaxf((acc.x - mu_) * rs * gv.x + bv.x, 0.f) + hv.x;
        o.y = fmaxf((acc.y - mu_) * rs * gv.y + bv.y, 0.f) + hv.y;
        o.z = fmaxf((acc.z - mu_) * rs * gv.z + bv.z, 0.f) + hv.z;
        o.w = fmaxf((acc.w - mu_) * rs * gv.w + bv.w, 0.f) + hv.w;
        h4[(size_t)n * 32 + sub] = o;
        ushort4 ob;
        ob.x = f2bf(o.x); ob.y = f2bf(o.y); ob.z = f2bf(o.z); ob.w = f2bf(o.w);
        ((ushort4*)hb)[(size_t)n * 32 + sub] = ob;
    }
}

// ---------------- launch ----------------

extern "C" void kernel_launch(void* const* d_in, const int* in_sizes, int n_in,
                              void* d_out, int out_size, void* d_ws, size_t ws_size,
                              hipStream_t stream) {
    const float* x    = (const float*)d_in[0];
    const int*   ei   = (const int*)d_in[1];
    const float* ew   = (const float*)d_in[2];
    const float* W_in = (const float*)d_in[3];
    const float* b_in = (const float*)d_in[4];
    const float* cW   = (const float*)d_in[5];
    const float* cb   = (const float*)d_in[6];
    const float* lg   = (const float*)d_in[7];
    const float* lb   = (const float*)d_in[8];
    float* h = (float*)d_out;

    char* ws = (char*)d_ws;
    unsigned long long* pk = (unsigned long long*)(ws + 0);   // 50000 u64 (400 KB)
    int*    rowp     = (int*)   (ws + 401408);                // 50001
    int*    rowp_tmp = (int*)   (ws + 602112);
    int*    bsum     = (int*)   (ws + 802816);                // 64
    int*    boff     = (int*)   (ws + 803072);                // 64
    uint*   erec     = (uint*)  (ws + 803328);                // ECAP u32 (4.6 MB)
    float*  dinv     = (float*) (ws + 5403328);               // 50000 f32
    ushort* Wp       = (ushort*)(ws + 5603328);               // 4*16384 bf16 (128 KB)
    signed char* m8  = (signed char*)(ws + 5734400);          // 50000*128 i8 (6.4 MB)
    int*    ord      = (int*)   (ws + 5734400);               // aliases m8 (dead until gemm)
    float*  sc       = (float*) (ws + 12134400);              // 50000 f32 row scales
    ushort* hb       = (ushort*)(ws + 12334400);              // 50000*128 bf16 (12.8 MB)

    const int NB = (NN + 1023) / 1024;                        // 49

    k_zero<<<(100000 / 4 + 255) / 256, 256, 0, stream>>>((int4*)pk, 100000 / 4);
    k_deg_cnt<<<(NE + 255) / 256, 256, 0, stream>>>(ei, ew, pk, ord);
    k_scan_a<<<NB, 1024, 0, stream>>>(pk, rowp_tmp, bsum, dinv);
    k_scan_b<<<1, 64, 0, stream>>>(bsum, boff, rowp, NB);
    k_scan_c<<<NB, 1024, 0, stream>>>(rowp_tmp, boff, pk, rowp, erec);
    k_scatter<<<(NE + 255) / 256, 256, 0, stream>>>(ei, ew, dinv, rowp, ord, erec);
    k_wpack<<<32, 256, 0, stream>>>(cW, Wp);

    k_inproj<<<(NN + 63) / 64, 256, 0, stream>>>(x, W_in, b_in, h, hb);

    for (int l = 0; l < NL; l++) {
        k_gemm<<<(NN + 63) / 64, 256, 0, stream>>>(hb, Wp + (size_t)l * 16384, m8, sc);
        k_agg<<<(NN + 3) / 4, 256, 0, stream>>>(m8, sc, rowp, erec, dinv,
                                                cb + l * HID, lg + l * HID, lb + l * HID, h, hb);
    }
}

// Round 15
// 277.754 us; speedup vs baseline: 1.2125x; 1.0287x over previous
//
#include <hip/hip_runtime.h>
#include <hip/hip_bf16.h>

#define NN 50000
#define NE 800000
#define IN_CH 64
#define HID 128
#define NL 4
#define LN_EPS 1e-5f

// padded CSR capacity: NE + 7*NN = 1,150,000
#define ECAP 1150000
#define WSCALE 1048576.0f   // 2^20 fixed point for edge-weight sums
#define VSCALE 32767.0f     // Q15 for packed edge values

typedef __attribute__((ext_vector_type(8))) short s8v;
typedef __attribute__((ext_vector_type(4))) float f4v;

__device__ inline ushort f2bf(float x) {
    __hip_bfloat16 h = __float2bfloat16(x);
    return *(ushort*)&h;
}
__device__ inline float4 i8u(uint u) {
    float4 r;
    r.x = (float)(int)(signed char)(u & 0xffu);
    r.y = (float)(int)(signed char)((u >> 8) & 0xffu);
    r.z = (float)(int)(signed char)((u >> 16) & 0xffu);
    r.w = (float)(int)(signed char)(u >> 24);
    return r;
}

// ---------------- preprocessing ----------------

__global__ void k_zero(int4* __restrict__ p, int n4) {
    int i = blockIdx.x * blockDim.x + threadIdx.x;
    if (i < n4) p[i] = make_int4(0, 0, 0, 0);
}

// one packed 64-bit atomic per edge: hi32 = count, lo32 = Q20 weight sum.
// unpadded pk: ~8 nodes/64B line amortizes one line over ~128 atomics (r12 lesson).
__global__ void k_deg_cnt(const int* __restrict__ ei, const float* __restrict__ ew,
                          unsigned long long* __restrict__ pk, int* __restrict__ ord) {
    int e = blockIdx.x * blockDim.x + threadIdx.x;
    if (e >= NE) return;
    int d = ei[NE + e];
    unsigned int wq = (unsigned int)__float2uint_rn(ew[e] * WSCALE);
    unsigned long long old = atomicAdd(&pk[d], (1ULL << 32) | (unsigned long long)wq);
    ord[e] = (int)(old >> 32);
}

// hierarchical scan of padded counts ((cnt+7)&~7) -> rowp (exclusive); fused dinv
__global__ __launch_bounds__(1024) void k_scan_a(const unsigned long long* __restrict__ pk,
                                                 int* __restrict__ rowp_tmp,
                                                 int* __restrict__ bsum,
                                                 float* __restrict__ dinv) {
    __shared__ int wsum[16];
    int tid = threadIdx.x;
    int lane = tid & 63, wv = tid >> 6;
    int i = blockIdx.x * 1024 + tid;
    unsigned long long pv = (i < NN) ? pk[i] : 0ULL;
    if (i < NN) {
        float deg = (float)(unsigned int)(pv & 0xffffffffu) * (1.0f / WSCALE);
        dinv[i] = rsqrtf(deg + 1.0f);
    }
    int v = (((int)(pv >> 32) + 7) & ~7);
    int s = v;
#pragma unroll
    for (int off = 1; off < 64; off <<= 1) {
        int t = __shfl_up(s, off, 64);
        if (lane >= off) s += t;
    }
    if (lane == 63) wsum[wv] = s;
    __syncthreads();
    int woff = 0;
    for (int w = 0; w < wv; w++) woff += wsum[w];
    if (i < NN) rowp_tmp[i] = woff + s - v;
    if (tid == 1023) bsum[blockIdx.x] = woff + s;
}

__global__ __launch_bounds__(64) void k_scan_b(const int* __restrict__ bsum,
                                               int* __restrict__ boff,
                                               int* __restrict__ rowp, int nb) {
    int t = threadIdx.x;
    int v = (t < nb) ? bsum[t] : 0;
    int s = v;
#pragma unroll
    for (int off = 1; off < 64; off <<= 1) {
        int u = __shfl_up(s, off, 64);
        if (t >= off) s += u;
    }
    if (t < nb) boff[t] = s - v;
    if (t == 63) rowp[NN] = s;
}

// phase c: finalize rowp AND zero the padding slots (fused k_pad)
__global__ __launch_bounds__(1024) void k_scan_c(const int* __restrict__ rowp_tmp,
                                                 const int* __restrict__ boff,
                                                 const unsigned long long* __restrict__ pk,
                                                 int* __restrict__ rowp,
                                                 uint* __restrict__ erec) {
    int i = blockIdx.x * 1024 + threadIdx.x;
    if (i >= NN) return;
    int start = rowp_tmp[i] + boff[blockIdx.x];
    rowp[i] = start;
    int cnt = (int)(pk[i] >> 32);
    int v = (cnt + 7) & ~7;
    for (int p = start + cnt; p < start + v; p++) erec[p] = 0u;
}

// atomic-free scatter: pos = rowp[d] + ord[e]; one u32 record (src<<15 | Q15 val)
__global__ void k_scatter(const int* __restrict__ ei, const float* __restrict__ ew,
                          const float* __restrict__ dinv, const int* __restrict__ rowp,
                          const int* __restrict__ ord, uint* __restrict__ erec) {
    int e = blockIdx.x * blockDim.x + threadIdx.x;
    if (e >= NE) return;
    int s = ei[e];
    int d = ei[NE + e];
    int pos = rowp[d] + ord[e];
    float v = dinv[s] * ew[e] * dinv[d];               // in (0, 1]
    uint q = (uint)__float2int_rn(v * VSCALE);
    erec[pos] = ((uint)s << 15) | q;
}

// ---------------- W repack for MFMA: all layers at once ----------------
__global__ __launch_bounds__(256) void k_wpack(const float* __restrict__ cW,
                                               ushort* __restrict__ Wp) {
    int gid = blockIdx.x * 256 + threadIdx.x;          // 0 .. 8191
    int lane = gid & 63;
    int t = (gid >> 6) & 7;
    int kc = (gid >> 9) & 3;
    int layer = gid >> 11;
    const float* W = cW + (size_t)layer * HID * HID;
    int kbase = kc * 32 + (lane >> 4) * 8;
    int col = t * 16 + (lane & 15);
    ushort o[8];
#pragma unroll
    for (int j = 0; j < 8; j++) o[j] = f2bf(W[(size_t)(kbase + j) * HID + col]);
    uint4 pk4;
    pk4.x = (uint)o[0] | ((uint)o[1] << 16);
    pk4.y = (uint)o[2] | ((uint)o[3] << 16);
    pk4.z = (uint)o[4] | ((uint)o[5] << 16);
    pk4.w = (uint)o[6] | ((uint)o[7] << 16);
    ((uint4*)Wp)[gid] = pk4;
}

// ---------------- input projection: h = relu(x @ W_in + b_in) ----------------
__global__ __launch_bounds__(256) void k_inproj(const float* __restrict__ x,
                                                const float* __restrict__ W,
                                                const float* __restrict__ b,
                                                float* __restrict__ h) {
    __shared__ float xs[64][IN_CH];
    int tid = threadIdx.x;
    int cx = tid & 31;
    int ny = tid >> 5;
    int nbase = blockIdx.x * 64;
    const float4* xg = (const float4*)(x + (size_t)nbase * IN_CH);
    float4* xs4 = (float4*)xs;
#pragma unroll
    for (int p = 0; p < 4; p++) {
        int i = p * 256 + tid;
        int row = i >> 4;
        xs4[i] = (nbase + row < NN) ? xg[i] : make_float4(0, 0, 0, 0);
    }
    __syncthreads();
    float4 acc[8];
#pragma unroll
    for (int j = 0; j < 8; j++) acc[j] = make_float4(0, 0, 0, 0);
    const float4* W4 = (const float4*)W;
#pragma unroll 4
    for (int k4 = 0; k4 < IN_CH / 4; k4++) {
        int k = 4 * k4;
        float4 w0 = W4[(k + 0) * 32 + cx];
        float4 w1 = W4[(k + 1) * 32 + cx];
        float4 w2 = W4[(k + 2) * 32 + cx];
        float4 w3 = W4[(k + 3) * 32 + cx];
#pragma unroll
        for (int j = 0; j < 8; j++) {
            float4 hv = *(const float4*)&xs[ny * 8 + j][k];
            acc[j].x += hv.x * w0.x + hv.y * w1.x + hv.z * w2.x + hv.w * w3.x;
            acc[j].y += hv.x * w0.y + hv.y * w1.y + hv.z * w2.y + hv.w * w3.y;
            acc[j].z += hv.x * w0.z + hv.y * w1.z + hv.z * w2.z + hv.w * w3.z;
            acc[j].w += hv.x * w0.w + hv.y * w1.w + hv.z * w2.w + hv.w * w3.w;
        }
    }
    float4 bc = ((const float4*)b)[cx];
    float4* mg = (float4*)h;
#pragma unroll
    for (int j = 0; j < 8; j++) {
        int n = nbase + ny * 8 + j;
        if (n < NN) {
            float4 o;
            o.x = fmaxf(acc[j].x + bc.x, 0.f);
            o.y = fmaxf(acc[j].y + bc.y, 0.f);
            o.z = fmaxf(acc[j].z + bc.z, 0.f);
            o.w = fmaxf(acc[j].w + bc.w, 0.f);
            mg[n * 32 + cx] = o;
        }
    }
}

// ---------------- per-layer GEMM via MFMA: m8(int8, per-row scale) = h(f32->bf16) @ W_l ----------------
__global__ __launch_bounds__(256) void k_gemm(const float* __restrict__ h,
                                              const ushort* __restrict__ Wp,
                                              signed char* __restrict__ m8,
                                              float* __restrict__ sc) {
    int tid = threadIdx.x;
    int w = tid >> 6, l = tid & 63;
    int q = l >> 4, r16 = l & 15;
    int rowbase = blockIdx.x * 64 + w * 16;
    f4v acc[8];
#pragma unroll
    for (int t = 0; t < 8; t++) acc[t] = (f4v){0.f, 0.f, 0.f, 0.f};
    const s8v* wp = (const s8v*)Wp;
    int row = rowbase + r16;
#pragma unroll
    for (int kc = 0; kc < 4; kc++) {
        s8v afrag;
        if (row < NN) {
            const float4* hp = (const float4*)(h + (size_t)row * HID + kc * 32 + q * 8);
            float4 h0 = hp[0], h1 = hp[1];
            afrag[0] = (short)f2bf(h0.x); afrag[1] = (short)f2bf(h0.y);
            afrag[2] = (short)f2bf(h0.z); afrag[3] = (short)f2bf(h0.w);
            afrag[4] = (short)f2bf(h1.x); afrag[5] = (short)f2bf(h1.y);
            afrag[6] = (short)f2bf(h1.z); afrag[7] = (short)f2bf(h1.w);
        } else {
            afrag = (s8v){0, 0, 0, 0, 0, 0, 0, 0};
        }
#pragma unroll
        for (int t = 0; t < 8; t++) {
            s8v bfrag = wp[(kc * 8 + t) * 64 + l];
            acc[t] = __builtin_amdgcn_mfma_f32_16x16x32_bf16(afrag, bfrag, acc[t], 0, 0, 0);
        }
    }
    // C/D layout: col = l&15, row = (l>>4)*4 + reg.
    // Per output row: |max| over 8 regs + 16-lane reduce -> int8 quant + scale.
#pragma unroll
    for (int rg = 0; rg < 4; rg++) {
        float rmax = 0.f;
#pragma unroll
        for (int t = 0; t < 8; t++) rmax = fmaxf(rmax, fabsf(acc[t][rg]));
#pragma unroll
        for (int off = 1; off < 16; off <<= 1)
            rmax = fmaxf(rmax, __shfl_xor(rmax, off, 16));
        rmax = fmaxf(rmax, 1e-20f);
        float scale = rmax * (1.0f / 127.0f);
        float inv = 127.0f / rmax;
        int orow = rowbase + q * 4 + rg;
        if (orow < NN) {
#pragma unroll
            for (int t = 0; t < 8; t++) {
                int qi = __float2int_rn(acc[t][rg] * inv);
                m8[(size_t)orow * HID + t * 16 + r16] = (signed char)qi;
            }
            if (r16 == 0) sc[orow] = scale;
        }
    }
}

// ---------------- aggregate + bias + LN + relu + residual (in-place h) ----------------
// one wave per node, 2 half-waves gather different edges' rows (uint = 4 int8 ch/lane).
// 8 edges/iter from 2 broadcast uint4 record loads.  (r8 structure, int8 rows)
__global__ __launch_bounds__(256) void k_agg(const signed char* __restrict__ m8,
                                             const float* __restrict__ sc,
                                             const int* __restrict__ rowp,
                                             const uint* __restrict__ erec,
                                             const float* __restrict__ dinv,
                                             const float* __restrict__ cb,
                                             const float* __restrict__ g,
                                             const float* __restrict__ bb,
                                             float* __restrict__ h) {
    int lane = threadIdx.x & 63;
    int sub = lane & 31;           // channel quad: 4*sub..4*sub+3
    int hi = lane >> 5;            // which edge of the pair
    int n = blockIdx.x * 4 + (threadIdx.x >> 6);
    if (n >= NN) return;
    const uint* mu = (const uint*)m8;
    float dn = dinv[n];
    float selfs = hi ? 0.0f : dn * dn * sc[n];
    float4 sv = i8u(mu[(size_t)n * 32 + sub]);
    float4 a0, a1, a2, a3;
    a0.x = selfs * sv.x; a0.y = selfs * sv.y; a0.z = selfs * sv.z; a0.w = selfs * sv.w;
    a1 = make_float4(0, 0, 0, 0);
    a2 = make_float4(0, 0, 0, 0);
    a3 = make_float4(0, 0, 0, 0);
    int r0 = rowp[n], r1 = rowp[n + 1];          // multiples of 8
    const uint4* e4 = (const uint4*)erec;
    for (int r = r0; r < r1; r += 8) {
        int qb = r >> 2;
        uint4 rA = e4[qb + 0];                   // edges r .. r+3
        uint4 rB = e4[qb + 1];                   // edges r+4 .. r+7
        uint c0 = hi ? rA.y : rA.x;
        uint c1 = hi ? rA.w : rA.z;
        uint c2 = hi ? rB.y : rB.x;
        uint c3 = hi ? rB.w : rB.z;
        int s0 = c0 >> 15;  int s1 = c1 >> 15;
        int s2 = c2 >> 15;  int s3 = c3 >> 15;
        float v0 = (float)(c0 & 32767u) * (1.0f / VSCALE) * sc[s0];
        float v1 = (float)(c1 & 32767u) * (1.0f / VSCALE) * sc[s1];
        float v2 = (float)(c2 & 32767u) * (1.0f / VSCALE) * sc[s2];
        float v3 = (float)(c3 & 32767u) * (1.0f / VSCALE) * sc[s3];
        float4 f0 = i8u(mu[(size_t)s0 * 32 + sub]);
        float4 f1 = i8u(mu[(size_t)s1 * 32 + sub]);
        float4 f2 = i8u(mu[(size_t)s2 * 32 + sub]);
        float4 f3 = i8u(mu[(size_t)s3 * 32 + sub]);
        a0.x += v0 * f0.x; a0.y += v0 * f0.y; a0.z += v0 * f0.z; a0.w += v0 * f0.w;
        a1.x += v1 * f1.x; a1.y += v1 * f1.y; a1.z += v1 * f1.z; a1.w += v1 * f1.w;
        a2.x += v2 * f2.x; a2.y += v2 * f2.y; a2.z += v2 * f2.z; a2.w += v2 * f2.w;
        a3.x += v3 * f3.x; a3.y += v3 * f3.y; a3.z += v3 * f3.z; a3.w += v3 * f3.w;
    }
    float4 acc;
    acc.x = a0.x + a1.x + a2.x + a3.x;
    acc.y = a0.y + a1.y + a2.y + a3.y;
    acc.z = a0.z + a1.z + a2.z + a3.z;
    acc.w = a0.w + a1.w + a2.w + a3.w;
    // combine the two half-wave partial sums (lane l <-> l^32)
    acc.x += __shfl_xor(acc.x, 32, 64);
    acc.y += __shfl_xor(acc.y, 32, 64);
    acc.z += __shfl_xor(acc.z, 32, 64);
    acc.w += __shfl_xor(acc.w, 32, 64);
    float4 cbv = ((const float4*)cb)[sub];
    acc.x += cbv.x; acc.y += cbv.y; acc.z += cbv.z; acc.w += cbv.w;
    // LayerNorm over 128 channels: reduce across 32 lanes (both halves identical)
    float s1 = acc.x + acc.y + acc.z + acc.w;
    float s2 = acc.x * acc.x + acc.y * acc.y + acc.z * acc.z + acc.w * acc.w;
#pragma unroll
    for (int off = 16; off > 0; off >>= 1) {
        s1 += __shfl_down(s1, off, 32);
        s2 += __shfl_down(s2, off, 32);
    }
    s1 = __shfl(s1, 0, 32);
    s2 = __shfl(s2, 0, 32);
    float mu_ = s1 * (1.0f / HID);
    float var = s2 * (1.0f / HID) - mu_ * mu_;
    float rs = rsqrtf(var + LN_EPS);
    if (hi == 0) {
        float4 gv = ((const float4*)g)[sub];
        float4 bv = ((const float4*)bb)[sub];
        float4* h4 = (float4*)h;
        float4 hv = h4[(size_t)n * 32 + sub];
        float4 o;
        o.x = fmaxf((acc.x - mu_) * rs * gv.x + bv.x, 0.f) + hv.x;
        o.y = fmaxf((acc.y - mu_) * rs * gv.y + bv.y, 0.f) + hv.y;
        o.z = fmaxf((acc.z - mu_) * rs * gv.z + bv.z, 0.f) + hv.z;
        o.w = fmaxf((acc.w - mu_) * rs * gv.w + bv.w, 0.f) + hv.w;
        h4[(size_t)n * 32 + sub] = o;
    }
}

// ---------------- launch ----------------

extern "C" void kernel_launch(void* const* d_in, const int* in_sizes, int n_in,
                              void* d_out, int out_size, void* d_ws, size_t ws_size,
                              hipStream_t stream) {
    const float* x    = (const float*)d_in[0];
    const int*   ei   = (const int*)d_in[1];
    const float* ew   = (const float*)d_in[2];
    const float* W_in = (const float*)d_in[3];
    const float* b_in = (const float*)d_in[4];
    const float* cW   = (const float*)d_in[5];
    const float* cb   = (const float*)d_in[6];
    const float* lg   = (const float*)d_in[7];
    const float* lb   = (const float*)d_in[8];
    float* h = (float*)d_out;

    char* ws = (char*)d_ws;
    unsigned long long* pk = (unsigned long long*)(ws + 0);   // 50000 u64 (400 KB)
    int*    rowp     = (int*)   (ws + 401408);                // 50001
    int*    rowp_tmp = (int*)   (ws + 602112);
    int*    bsum     = (int*)   (ws + 802816);                // 64
    int*    boff     = (int*)   (ws + 803072);                // 64
    uint*   erec     = (uint*)  (ws + 803328);                // ECAP u32 (4.6 MB)
    float*  dinv     = (float*) (ws + 5403328);               // 50000 f32
    ushort* Wp       = (ushort*)(ws + 5603328);               // 4*16384 bf16 (128 KB)
    signed char* m8  = (signed char*)(ws + 5734400);          // 50000*128 i8 (6.4 MB)
    int*    ord      = (int*)   (ws + 5734400);               // aliases m8 (dead until gemm)
    float*  sc       = (float*) (ws + 12134400);              // 50000 f32 row scales

    const int NB = (NN + 1023) / 1024;                        // 49

    k_zero<<<(100000 / 4 + 255) / 256, 256, 0, stream>>>((int4*)pk, 100000 / 4);
    k_deg_cnt<<<(NE + 255) / 256, 256, 0, stream>>>(ei, ew, pk, ord);
    k_scan_a<<<NB, 1024, 0, stream>>>(pk, rowp_tmp, bsum, dinv);
    k_scan_b<<<1, 64, 0, stream>>>(bsum, boff, rowp, NB);
    k_scan_c<<<NB, 1024, 0, stream>>>(rowp_tmp, boff, pk, rowp, erec);
    k_scatter<<<(NE + 255) / 256, 256, 0, stream>>>(ei, ew, dinv, rowp, ord, erec);
    k_wpack<<<32, 256, 0, stream>>>(cW, Wp);

    k_inproj<<<(NN + 63) / 64, 256, 0, stream>>>(x, W_in, b_in, h);

    for (int l = 0; l < NL; l++) {
        k_gemm<<<(NN + 63) / 64, 256, 0, stream>>>(h, Wp + (size_t)l * 16384, m8, sc);
        k_agg<<<(NN + 3) / 4, 256, 0, stream>>>(m8, sc, rowp, erec, dinv,
                                                cb + l * HID, lg + l * HID, lb + l * HID, h);
    }
}

// Round 16
// 268.273 us; speedup vs baseline: 1.2554x; 1.0353x over previous
//
#include <hip/hip_runtime.h>
#include <hip/hip_bf16.h>

#define NN 50000
#define NE 800000
#define IN_CH 64
#define HID 128
#define NL 4
#define LN_EPS 1e-5f

// padded CSR capacity: NE + 7*NN = 1,150,000
#define ECAP 1150000
#define WSCALE 1048576.0f   // 2^20 fixed point for edge-weight sums
#define VSCALE 32767.0f     // Q15 for packed edge values

// fused-dispatch block-range sizes
#define NB_DEG  3125        // (NE+255)/256
#define NB_INP  782         // (NN+63)/64
#define NB_WP   32
#define NB_SCAT 3125
#define NB_GEMM 782

typedef __attribute__((ext_vector_type(8))) short s8v;
typedef __attribute__((ext_vector_type(4))) float f4v;

__device__ inline ushort f2bf(float x) {
    __hip_bfloat16 h = __float2bfloat16(x);
    return *(ushort*)&h;
}
__device__ inline float4 i8u(uint u) {
    float4 r;
    r.x = (float)(int)(signed char)(u & 0xffu);
    r.y = (float)(int)(signed char)((u >> 8) & 0xffu);
    r.z = (float)(int)(signed char)((u >> 16) & 0xffu);
    r.w = (float)(int)(signed char)(u >> 24);
    return r;
}

// ---------------- device bodies for fused dispatches ----------------

// deg/cnt: one packed u64 atomic per edge (hi32 = count, lo32 = Q20 weight sum).
// unpadded pk: ~8 nodes/64B line amortizes one line over ~128 atomics (r12 lesson).
__device__ inline void do_deg(int blk, const int* __restrict__ ei,
                              const float* __restrict__ ew,
                              unsigned long long* __restrict__ pk,
                              int* __restrict__ ord) {
    int e = blk * 256 + threadIdx.x;
    if (e >= NE) return;
    int d = ei[NE + e];
    unsigned int wq = (unsigned int)__float2uint_rn(ew[e] * WSCALE);
    unsigned long long old = atomicAdd(&pk[d], (1ULL << 32) | (unsigned long long)wq);
    ord[e] = (int)(old >> 32);
}

// input projection: h = relu(x @ W_in + b_in); 64-node tile in LDS
__device__ inline void do_inproj(int blk, const float* __restrict__ x,
                                 const float* __restrict__ W,
                                 const float* __restrict__ b,
                                 float* __restrict__ h) {
    __shared__ float xs[64][IN_CH];
    int tid = threadIdx.x;
    int cx = tid & 31;
    int ny = tid >> 5;
    int nbase = blk * 64;
    const float4* xg = (const float4*)(x + (size_t)nbase * IN_CH);
    float4* xs4 = (float4*)xs;
#pragma unroll
    for (int p = 0; p < 4; p++) {
        int i = p * 256 + tid;
        int row = i >> 4;
        xs4[i] = (nbase + row < NN) ? xg[i] : make_float4(0, 0, 0, 0);
    }
    __syncthreads();
    float4 acc[8];
#pragma unroll
    for (int j = 0; j < 8; j++) acc[j] = make_float4(0, 0, 0, 0);
    const float4* W4 = (const float4*)W;
#pragma unroll 4
    for (int k4 = 0; k4 < IN_CH / 4; k4++) {
        int k = 4 * k4;
        float4 w0 = W4[(k + 0) * 32 + cx];
        float4 w1 = W4[(k + 1) * 32 + cx];
        float4 w2 = W4[(k + 2) * 32 + cx];
        float4 w3 = W4[(k + 3) * 32 + cx];
#pragma unroll
        for (int j = 0; j < 8; j++) {
            float4 hv = *(const float4*)&xs[ny * 8 + j][k];
            acc[j].x += hv.x * w0.x + hv.y * w1.x + hv.z * w2.x + hv.w * w3.x;
            acc[j].y += hv.x * w0.y + hv.y * w1.y + hv.z * w2.y + hv.w * w3.y;
            acc[j].z += hv.x * w0.z + hv.y * w1.z + hv.z * w2.z + hv.w * w3.z;
            acc[j].w += hv.x * w0.w + hv.y * w1.w + hv.z * w2.w + hv.w * w3.w;
        }
    }
    float4 bc = ((const float4*)b)[cx];
    float4* mg = (float4*)h;
#pragma unroll
    for (int j = 0; j < 8; j++) {
        int n = nbase + ny * 8 + j;
        if (n < NN) {
            float4 o;
            o.x = fmaxf(acc[j].x + bc.x, 0.f);
            o.y = fmaxf(acc[j].y + bc.y, 0.f);
            o.z = fmaxf(acc[j].z + bc.z, 0.f);
            o.w = fmaxf(acc[j].w + bc.w, 0.f);
            mg[n * 32 + cx] = o;
        }
    }
}

// W repack for MFMA (all 4 layers)
__device__ inline void do_wpack(int blk, const float* __restrict__ cW,
                                ushort* __restrict__ Wp) {
    int gid = blk * 256 + threadIdx.x;                 // 0 .. 8191
    int lane = gid & 63;
    int t = (gid >> 6) & 7;
    int kc = (gid >> 9) & 3;
    int layer = gid >> 11;
    const float* W = cW + (size_t)layer * HID * HID;
    int kbase = kc * 32 + (lane >> 4) * 8;
    int col = t * 16 + (lane & 15);
    ushort o[8];
#pragma unroll
    for (int j = 0; j < 8; j++) o[j] = f2bf(W[(size_t)(kbase + j) * HID + col]);
    uint4 pk4;
    pk4.x = (uint)o[0] | ((uint)o[1] << 16);
    pk4.y = (uint)o[2] | ((uint)o[3] << 16);
    pk4.z = (uint)o[4] | ((uint)o[5] << 16);
    pk4.w = (uint)o[6] | ((uint)o[7] << 16);
    ((uint4*)Wp)[gid] = pk4;
}

// atomic-free scatter: pos = rowp[d] + ord[e]; one u32 record (src<<15 | Q15 val)
__device__ inline void do_scatter(int blk, const int* __restrict__ ei,
                                  const float* __restrict__ ew,
                                  const float* __restrict__ dinv,
                                  const int* __restrict__ rowp,
                                  const int* __restrict__ ord,
                                  uint* __restrict__ erec) {
    int e = blk * 256 + threadIdx.x;
    if (e >= NE) return;
    int s = ei[e];
    int d = ei[NE + e];
    int pos = rowp[d] + ord[e];
    float v = dinv[s] * ew[e] * dinv[d];               // in (0, 1]
    uint q = (uint)__float2int_rn(v * VSCALE);
    erec[pos] = ((uint)s << 15) | q;
}

// per-layer GEMM via MFMA: m8(int8, per-row scale) = h(f32->bf16) @ W_l
__device__ inline void do_gemm(int blk, const float* __restrict__ h,
                               const ushort* __restrict__ Wp,
                               signed char* __restrict__ m8,
                               float* __restrict__ sc) {
    int tid = threadIdx.x;
    int w = tid >> 6, l = tid & 63;
    int q = l >> 4, r16 = l & 15;
    int rowbase = blk * 64 + w * 16;
    f4v acc[8];
#pragma unroll
    for (int t = 0; t < 8; t++) acc[t] = (f4v){0.f, 0.f, 0.f, 0.f};
    const s8v* wp = (const s8v*)Wp;
    int row = rowbase + r16;
#pragma unroll
    for (int kc = 0; kc < 4; kc++) {
        s8v afrag;
        if (row < NN) {
            const float4* hp = (const float4*)(h + (size_t)row * HID + kc * 32 + q * 8);
            float4 h0 = hp[0], h1 = hp[1];
            afrag[0] = (short)f2bf(h0.x); afrag[1] = (short)f2bf(h0.y);
            afrag[2] = (short)f2bf(h0.z); afrag[3] = (short)f2bf(h0.w);
            afrag[4] = (short)f2bf(h1.x); afrag[5] = (short)f2bf(h1.y);
            afrag[6] = (short)f2bf(h1.z); afrag[7] = (short)f2bf(h1.w);
        } else {
            afrag = (s8v){0, 0, 0, 0, 0, 0, 0, 0};
        }
#pragma unroll
        for (int t = 0; t < 8; t++) {
            s8v bfrag = wp[(kc * 8 + t) * 64 + l];
            acc[t] = __builtin_amdgcn_mfma_f32_16x16x32_bf16(afrag, bfrag, acc[t], 0, 0, 0);
        }
    }
    // C/D layout: col = l&15, row = (l>>4)*4 + reg.
#pragma unroll
    for (int rg = 0; rg < 4; rg++) {
        float rmax = 0.f;
#pragma unroll
        for (int t = 0; t < 8; t++) rmax = fmaxf(rmax, fabsf(acc[t][rg]));
#pragma unroll
        for (int off = 1; off < 16; off <<= 1)
            rmax = fmaxf(rmax, __shfl_xor(rmax, off, 16));
        rmax = fmaxf(rmax, 1e-20f);
        float scale = rmax * (1.0f / 127.0f);
        float inv = 127.0f / rmax;
        int orow = rowbase + q * 4 + rg;
        if (orow < NN) {
#pragma unroll
            for (int t = 0; t < 8; t++) {
                int qi = __float2int_rn(acc[t][rg] * inv);
                m8[(size_t)orow * HID + t * 16 + r16] = (signed char)qi;
            }
            if (r16 == 0) sc[orow] = scale;
        }
    }
}

// ---------------- fused dispatches ----------------

// phase 1: deg/cnt atomics (long pole, blocks first) || inproj || wpack
__global__ __launch_bounds__(256) void k_pre(const int* __restrict__ ei,
                                             const float* __restrict__ ew,
                                             unsigned long long* __restrict__ pk,
                                             int* __restrict__ ord,
                                             const float* __restrict__ x,
                                             const float* __restrict__ W_in,
                                             const float* __restrict__ b_in,
                                             float* __restrict__ h,
                                             const float* __restrict__ cW,
                                             ushort* __restrict__ Wp) {
    int b = blockIdx.x;
    if (b < NB_DEG) {
        do_deg(b, ei, ew, pk, ord);
    } else if (b < NB_DEG + NB_INP) {
        do_inproj(b - NB_DEG, x, W_in, b_in, h);
    } else {
        do_wpack(b - NB_DEG - NB_INP, cW, Wp);
    }
}

// phase 2: scatter (long pole) || gemm layer 0
__global__ __launch_bounds__(256) void k_scat_gemm(const int* __restrict__ ei,
                                                   const float* __restrict__ ew,
                                                   const float* __restrict__ dinv,
                                                   const int* __restrict__ rowp,
                                                   const int* __restrict__ ord,
                                                   uint* __restrict__ erec,
                                                   const float* __restrict__ h,
                                                   const ushort* __restrict__ Wp,
                                                   signed char* __restrict__ m8,
                                                   float* __restrict__ sc) {
    int b = blockIdx.x;
    if (b < NB_SCAT) {
        do_scatter(b, ei, ew, dinv, rowp, ord, erec);
    } else {
        do_gemm(b - NB_SCAT, h, Wp, m8, sc);
    }
}

// ---------------- standalone kernels ----------------

__global__ void k_zero(int4* __restrict__ p, int n4) {
    int i = blockIdx.x * blockDim.x + threadIdx.x;
    if (i < n4) p[i] = make_int4(0, 0, 0, 0);
}

// hierarchical scan of padded counts ((cnt+7)&~7) -> rowp (exclusive); fused dinv
__global__ __launch_bounds__(1024) void k_scan_a(const unsigned long long* __restrict__ pk,
                                                 int* __restrict__ rowp_tmp,
                                                 int* __restrict__ bsum,
                                                 float* __restrict__ dinv) {
    __shared__ int wsum[16];
    int tid = threadIdx.x;
    int lane = tid & 63, wv = tid >> 6;
    int i = blockIdx.x * 1024 + tid;
    unsigned long long pv = (i < NN) ? pk[i] : 0ULL;
    if (i < NN) {
        float deg = (float)(unsigned int)(pv & 0xffffffffu) * (1.0f / WSCALE);
        dinv[i] = rsqrtf(deg + 1.0f);
    }
    int v = (((int)(pv >> 32) + 7) & ~7);
    int s = v;
#pragma unroll
    for (int off = 1; off < 64; off <<= 1) {
        int t = __shfl_up(s, off, 64);
        if (lane >= off) s += t;
    }
    if (lane == 63) wsum[wv] = s;
    __syncthreads();
    int woff = 0;
    for (int w = 0; w < wv; w++) woff += wsum[w];
    if (i < NN) rowp_tmp[i] = woff + s - v;
    if (tid == 1023) bsum[blockIdx.x] = woff + s;
}

__global__ __launch_bounds__(64) void k_scan_b(const int* __restrict__ bsum,
                                               int* __restrict__ boff,
                                               int* __restrict__ rowp, int nb) {
    int t = threadIdx.x;
    int v = (t < nb) ? bsum[t] : 0;
    int s = v;
#pragma unroll
    for (int off = 1; off < 64; off <<= 1) {
        int u = __shfl_up(s, off, 64);
        if (t >= off) s += u;
    }
    if (t < nb) boff[t] = s - v;
    if (t == 63) rowp[NN] = s;
}

// phase c: finalize rowp AND zero the padding slots (fused k_pad)
__global__ __launch_bounds__(1024) void k_scan_c(const int* __restrict__ rowp_tmp,
                                                 const int* __restrict__ boff,
                                                 const unsigned long long* __restrict__ pk,
                                                 int* __restrict__ rowp,
                                                 uint* __restrict__ erec) {
    int i = blockIdx.x * 1024 + threadIdx.x;
    if (i >= NN) return;
    int start = rowp_tmp[i] + boff[blockIdx.x];
    rowp[i] = start;
    int cnt = (int)(pk[i] >> 32);
    int v = (cnt + 7) & ~7;
    for (int p = start + cnt; p < start + v; p++) erec[p] = 0u;
}

__global__ __launch_bounds__(256) void k_gemm(const float* __restrict__ h,
                                              const ushort* __restrict__ Wp,
                                              signed char* __restrict__ m8,
                                              float* __restrict__ sc) {
    do_gemm(blockIdx.x, h, Wp, m8, sc);
}

// ---------------- aggregate + bias + LN + relu + residual (in-place h) ----------------
// one wave per node, 2 half-waves gather different edges' rows (uint = 4 int8 ch/lane).
// 8 edges/iter from 2 broadcast uint4 record loads.  (r8 structure, int8 rows)
__global__ __launch_bounds__(256) void k_agg(const signed char* __restrict__ m8,
                                             const float* __restrict__ sc,
                                             const int* __restrict__ rowp,
                                             const uint* __restrict__ erec,
                                             const float* __restrict__ dinv,
                                             const float* __restrict__ cb,
                                             const float* __restrict__ g,
                                             const float* __restrict__ bb,
                                             float* __restrict__ h) {
    int lane = threadIdx.x & 63;
    int sub = lane & 31;           // channel quad: 4*sub..4*sub+3
    int hi = lane >> 5;            // which edge of the pair
    int n = blockIdx.x * 4 + (threadIdx.x >> 6);
    if (n >= NN) return;
    const uint* mu = (const uint*)m8;
    float dn = dinv[n];
    float selfs = hi ? 0.0f : dn * dn * sc[n];
    float4 sv = i8u(mu[(size_t)n * 32 + sub]);
    float4 a0, a1, a2, a3;
    a0.x = selfs * sv.x; a0.y = selfs * sv.y; a0.z = selfs * sv.z; a0.w = selfs * sv.w;
    a1 = make_float4(0, 0, 0, 0);
    a2 = make_float4(0, 0, 0, 0);
    a3 = make_float4(0, 0, 0, 0);
    int r0 = rowp[n], r1 = rowp[n + 1];          // multiples of 8
    const uint4* e4 = (const uint4*)erec;
    for (int r = r0; r < r1; r += 8) {
        int qb = r >> 2;
        uint4 rA = e4[qb + 0];                   // edges r .. r+3
        uint4 rB = e4[qb + 1];                   // edges r+4 .. r+7
        uint c0 = hi ? rA.y : rA.x;
        uint c1 = hi ? rA.w : rA.z;
        uint c2 = hi ? rB.y : rB.x;
        uint c3 = hi ? rB.w : rB.z;
        int s0 = c0 >> 15;  int s1 = c1 >> 15;
        int s2 = c2 >> 15;  int s3 = c3 >> 15;
        float v0 = (float)(c0 & 32767u) * (1.0f / VSCALE) * sc[s0];
        float v1 = (float)(c1 & 32767u) * (1.0f / VSCALE) * sc[s1];
        float v2 = (float)(c2 & 32767u) * (1.0f / VSCALE) * sc[s2];
        float v3 = (float)(c3 & 32767u) * (1.0f / VSCALE) * sc[s3];
        float4 f0 = i8u(mu[(size_t)s0 * 32 + sub]);
        float4 f1 = i8u(mu[(size_t)s1 * 32 + sub]);
        float4 f2 = i8u(mu[(size_t)s2 * 32 + sub]);
        float4 f3 = i8u(mu[(size_t)s3 * 32 + sub]);
        a0.x += v0 * f0.x; a0.y += v0 * f0.y; a0.z += v0 * f0.z; a0.w += v0 * f0.w;
        a1.x += v1 * f1.x; a1.y += v1 * f1.y; a1.z += v1 * f1.z; a1.w += v1 * f1.w;
        a2.x += v2 * f2.x; a2.y += v2 * f2.y; a2.z += v2 * f2.z; a2.w += v2 * f2.w;
        a3.x += v3 * f3.x; a3.y += v3 * f3.y; a3.z += v3 * f3.z; a3.w += v3 * f3.w;
    }
    float4 acc;
    acc.x = a0.x + a1.x + a2.x + a3.x;
    acc.y = a0.y + a1.y + a2.y + a3.y;
    acc.z = a0.z + a1.z + a2.z + a3.z;
    acc.w = a0.w + a1.w + a2.w + a3.w;
    // combine the two half-wave partial sums (lane l <-> l^32)
    acc.x += __shfl_xor(acc.x, 32, 64);
    acc.y += __shfl_xor(acc.y, 32, 64);
    acc.z += __shfl_xor(acc.z, 32, 64);
    acc.w += __shfl_xor(acc.w, 32, 64);
    float4 cbv = ((const float4*)cb)[sub];
    acc.x += cbv.x; acc.y += cbv.y; acc.z += cbv.z; acc.w += cbv.w;
    // LayerNorm over 128 channels: reduce across 32 lanes (both halves identical)
    float s1 = acc.x + acc.y + acc.z + acc.w;
    float s2 = acc.x * acc.x + acc.y * acc.y + acc.z * acc.z + acc.w * acc.w;
#pragma unroll
    for (int off = 16; off > 0; off >>= 1) {
        s1 += __shfl_down(s1, off, 32);
        s2 += __shfl_down(s2, off, 32);
    }
    s1 = __shfl(s1, 0, 32);
    s2 = __shfl(s2, 0, 32);
    float mu_ = s1 * (1.0f / HID);
    float var = s2 * (1.0f / HID) - mu_ * mu_;
    float rs = rsqrtf(var + LN_EPS);
    if (hi == 0) {
        float4 gv = ((const float4*)g)[sub];
        float4 bv = ((const float4*)bb)[sub];
        float4* h4 = (float4*)h;
        float4 hv = h4[(size_t)n * 32 + sub];
        float4 o;
        o.x = fmaxf((acc.x - mu_) * rs * gv.x + bv.x, 0.f) + hv.x;
        o.y = fmaxf((acc.y - mu_) * rs * gv.y + bv.y, 0.f) + hv.y;
        o.z = fmaxf((acc.z - mu_) * rs * gv.z + bv.z, 0.f) + hv.z;
        o.w = fmaxf((acc.w - mu_) * rs * gv.w + bv.w, 0.f) + hv.w;
        h4[(size_t)n * 32 + sub] = o;
    }
}

// ---------------- launch ----------------

extern "C" void kernel_launch(void* const* d_in, const int* in_sizes, int n_in,
                              void* d_out, int out_size, void* d_ws, size_t ws_size,
                              hipStream_t stream) {
    const float* x    = (const float*)d_in[0];
    const int*   ei   = (const int*)d_in[1];
    const float* ew   = (const float*)d_in[2];
    const float* W_in = (const float*)d_in[3];
    const float* b_in = (const float*)d_in[4];
    const float* cW   = (const float*)d_in[5];
    const float* cb   = (const float*)d_in[6];
    const float* lg   = (const float*)d_in[7];
    const float* lb   = (const float*)d_in[8];
    float* h = (float*)d_out;

    char* ws = (char*)d_ws;
    unsigned long long* pk = (unsigned long long*)(ws + 0);   // 50000 u64 (400 KB)
    int*    rowp     = (int*)   (ws + 401408);                // 50001
    int*    rowp_tmp = (int*)   (ws + 602112);
    int*    bsum     = (int*)   (ws + 802816);                // 64
    int*    boff     = (int*)   (ws + 803072);                // 64
    uint*   erec     = (uint*)  (ws + 803328);                // ECAP u32 (4.6 MB)
    float*  dinv     = (float*) (ws + 5403328);               // 50000 f32
    ushort* Wp       = (ushort*)(ws + 5603328);               // 4*16384 bf16 (128 KB)
    signed char* m8  = (signed char*)(ws + 5734400);          // 50000*128 i8 (6.4 MB)
    float*  sc       = (float*) (ws + 12134400);              // 50000 f32 row scales
    int*    ord      = (int*)   (ws + 12334400);              // 800000 i32 (own buffer:
                                                              // alive across k_scat_gemm)

    const int NB = (NN + 1023) / 1024;                        // 49

    k_zero<<<(100000 / 4 + 255) / 256, 256, 0, stream>>>((int4*)pk, 100000 / 4);
    // deg atomics || input projection || W repack
    k_pre<<<NB_DEG + NB_INP + NB_WP, 256, 0, stream>>>(ei, ew, pk, ord,
                                                       x, W_in, b_in, h, cW, Wp);
    k_scan_a<<<NB, 1024, 0, stream>>>(pk, rowp_tmp, bsum, dinv);
    k_scan_b<<<1, 64, 0, stream>>>(bsum, boff, rowp, NB);
    k_scan_c<<<NB, 1024, 0, stream>>>(rowp_tmp, boff, pk, rowp, erec);
    // edge scatter || layer-0 GEMM
    k_scat_gemm<<<NB_SCAT + NB_GEMM, 256, 0, stream>>>(ei, ew, dinv, rowp, ord, erec,
                                                       h, Wp, m8, sc);

    k_agg<<<(NN + 3) / 4, 256, 0, stream>>>(m8, sc, rowp, erec, dinv,
                                            cb, lg, lb, h);
    for (int l = 1; l < NL; l++) {
        k_gemm<<<NB_GEMM, 256, 0, stream>>>(h, Wp + (size_t)l * 16384, m8, sc);
        k_agg<<<(NN + 3) / 4, 256, 0, stream>>>(m8, sc, rowp, erec, dinv,
                                                cb + l * HID, lg + l * HID, lb + l * HID, h);
    }
}

// Round 17
// 258.892 us; speedup vs baseline: 1.3008x; 1.0362x over previous
//
#include <hip/hip_runtime.h>
#include <hip/hip_bf16.h>

#define NN 50000
#define NE 800000
#define IN_CH 64
#define HID 128
#define NL 4
#define LN_EPS 1e-5f

// padded CSR capacity: NE + 7*NN = 1,150,000
#define ECAP 1150000
#define WSCALE 1048576.0f   // 2^20 fixed point for edge-weight sums
#define VSCALE 32767.0f     // Q15 for packed edge values

// fused-dispatch block counts
#define NB_DEG  3125        // (NE+255)/256
#define NB_INP  782         // (NN+63)/64
#define NB_WP   32
#define NB_C1   (NB_INP + NB_WP)   // 814 compute blocks in phase 1
#define NB_SCAT 3125
#define NB_GEMM 782

typedef __attribute__((ext_vector_type(8))) short s8v;
typedef __attribute__((ext_vector_type(4))) float f4v;

__device__ inline ushort f2bf(float x) {
    __hip_bfloat16 h = __float2bfloat16(x);
    return *(ushort*)&h;
}
__device__ inline float4 i8u(uint u) {
    float4 r;
    r.x = (float)(int)(signed char)(u & 0xffu);
    r.y = (float)(int)(signed char)((u >> 8) & 0xffu);
    r.z = (float)(int)(signed char)((u >> 16) & 0xffu);
    r.w = (float)(int)(signed char)(u >> 24);
    return r;
}

// ---------------- device bodies for fused dispatches ----------------

// deg/cnt: one packed u64 atomic per edge (hi32 = count, lo32 = Q20 weight sum).
__device__ inline void do_deg(int blk, const int* __restrict__ ei,
                              const float* __restrict__ ew,
                              unsigned long long* __restrict__ pk,
                              int* __restrict__ ord) {
    int e = blk * 256 + threadIdx.x;
    if (e >= NE) return;
    int d = ei[NE + e];
    unsigned int wq = (unsigned int)__float2uint_rn(ew[e] * WSCALE);
    unsigned long long old = atomicAdd(&pk[d], (1ULL << 32) | (unsigned long long)wq);
    ord[e] = (int)(old >> 32);
}

// input projection: h = relu(x @ W_in + b_in); 64-node tile in LDS
__device__ inline void do_inproj(int blk, const float* __restrict__ x,
                                 const float* __restrict__ W,
                                 const float* __restrict__ b,
                                 float* __restrict__ h) {
    __shared__ float xs[64][IN_CH];
    int tid = threadIdx.x;
    int cx = tid & 31;
    int ny = tid >> 5;
    int nbase = blk * 64;
    const float4* xg = (const float4*)(x + (size_t)nbase * IN_CH);
    float4* xs4 = (float4*)xs;
#pragma unroll
    for (int p = 0; p < 4; p++) {
        int i = p * 256 + tid;
        int row = i >> 4;
        xs4[i] = (nbase + row < NN) ? xg[i] : make_float4(0, 0, 0, 0);
    }
    __syncthreads();
    float4 acc[8];
#pragma unroll
    for (int j = 0; j < 8; j++) acc[j] = make_float4(0, 0, 0, 0);
    const float4* W4 = (const float4*)W;
#pragma unroll 4
    for (int k4 = 0; k4 < IN_CH / 4; k4++) {
        int k = 4 * k4;
        float4 w0 = W4[(k + 0) * 32 + cx];
        float4 w1 = W4[(k + 1) * 32 + cx];
        float4 w2 = W4[(k + 2) * 32 + cx];
        float4 w3 = W4[(k + 3) * 32 + cx];
#pragma unroll
        for (int j = 0; j < 8; j++) {
            float4 hv = *(const float4*)&xs[ny * 8 + j][k];
            acc[j].x += hv.x * w0.x + hv.y * w1.x + hv.z * w2.x + hv.w * w3.x;
            acc[j].y += hv.x * w0.y + hv.y * w1.y + hv.z * w2.y + hv.w * w3.y;
            acc[j].z += hv.x * w0.z + hv.y * w1.z + hv.z * w2.z + hv.w * w3.z;
            acc[j].w += hv.x * w0.w + hv.y * w1.w + hv.z * w2.w + hv.w * w3.w;
        }
    }
    float4 bc = ((const float4*)b)[cx];
    float4* mg = (float4*)h;
#pragma unroll
    for (int j = 0; j < 8; j++) {
        int n = nbase + ny * 8 + j;
        if (n < NN) {
            float4 o;
            o.x = fmaxf(acc[j].x + bc.x, 0.f);
            o.y = fmaxf(acc[j].y + bc.y, 0.f);
            o.z = fmaxf(acc[j].z + bc.z, 0.f);
            o.w = fmaxf(acc[j].w + bc.w, 0.f);
            mg[n * 32 + cx] = o;
        }
    }
}

// W repack for MFMA (all 4 layers)
__device__ inline void do_wpack(int blk, const float* __restrict__ cW,
                                ushort* __restrict__ Wp) {
    int gid = blk * 256 + threadIdx.x;                 // 0 .. 8191
    int lane = gid & 63;
    int t = (gid >> 6) & 7;
    int kc = (gid >> 9) & 3;
    int layer = gid >> 11;
    const float* W = cW + (size_t)layer * HID * HID;
    int kbase = kc * 32 + (lane >> 4) * 8;
    int col = t * 16 + (lane & 15);
    ushort o[8];
#pragma unroll
    for (int j = 0; j < 8; j++) o[j] = f2bf(W[(size_t)(kbase + j) * HID + col]);
    uint4 pk4;
    pk4.x = (uint)o[0] | ((uint)o[1] << 16);
    pk4.y = (uint)o[2] | ((uint)o[3] << 16);
    pk4.z = (uint)o[4] | ((uint)o[5] << 16);
    pk4.w = (uint)o[6] | ((uint)o[7] << 16);
    ((uint4*)Wp)[gid] = pk4;
}

// atomic-free scatter: pos = rowp[d] + ord[e]; one u32 record (src<<15 | Q15 val)
__device__ inline void do_scatter(int blk, const int* __restrict__ ei,
                                  const float* __restrict__ ew,
                                  const float* __restrict__ dinv,
                                  const int* __restrict__ rowp,
                                  const int* __restrict__ ord,
                                  uint* __restrict__ erec) {
    int e = blk * 256 + threadIdx.x;
    if (e >= NE) return;
    int s = ei[e];
    int d = ei[NE + e];
    int pos = rowp[d] + ord[e];
    float v = dinv[s] * ew[e] * dinv[d];               // in (0, 1]
    uint q = (uint)__float2int_rn(v * VSCALE);
    erec[pos] = ((uint)s << 15) | q;
}

// per-layer GEMM via MFMA: m8(int8, per-row scale) = h(f32->bf16) @ W_l
__device__ inline void do_gemm(int blk, const float* __restrict__ h,
                               const ushort* __restrict__ Wp,
                               signed char* __restrict__ m8,
                               float* __restrict__ sc) {
    int tid = threadIdx.x;
    int w = tid >> 6, l = tid & 63;
    int q = l >> 4, r16 = l & 15;
    int rowbase = blk * 64 + w * 16;
    f4v acc[8];
#pragma unroll
    for (int t = 0; t < 8; t++) acc[t] = (f4v){0.f, 0.f, 0.f, 0.f};
    const s8v* wp = (const s8v*)Wp;
    int row = rowbase + r16;
#pragma unroll
    for (int kc = 0; kc < 4; kc++) {
        s8v afrag;
        if (row < NN) {
            const float4* hp = (const float4*)(h + (size_t)row * HID + kc * 32 + q * 8);
            float4 h0 = hp[0], h1 = hp[1];
            afrag[0] = (short)f2bf(h0.x); afrag[1] = (short)f2bf(h0.y);
            afrag[2] = (short)f2bf(h0.z); afrag[3] = (short)f2bf(h0.w);
            afrag[4] = (short)f2bf(h1.x); afrag[5] = (short)f2bf(h1.y);
            afrag[6] = (short)f2bf(h1.z); afrag[7] = (short)f2bf(h1.w);
        } else {
            afrag = (s8v){0, 0, 0, 0, 0, 0, 0, 0};
        }
#pragma unroll
        for (int t = 0; t < 8; t++) {
            s8v bfrag = wp[(kc * 8 + t) * 64 + l];
            acc[t] = __builtin_amdgcn_mfma_f32_16x16x32_bf16(afrag, bfrag, acc[t], 0, 0, 0);
        }
    }
    // C/D layout: col = l&15, row = (l>>4)*4 + reg.
#pragma unroll
    for (int rg = 0; rg < 4; rg++) {
        float rmax = 0.f;
#pragma unroll
        for (int t = 0; t < 8; t++) rmax = fmaxf(rmax, fabsf(acc[t][rg]));
#pragma unroll
        for (int off = 1; off < 16; off <<= 1)
            rmax = fmaxf(rmax, __shfl_xor(rmax, off, 16));
        rmax = fmaxf(rmax, 1e-20f);
        float scale = rmax * (1.0f / 127.0f);
        float inv = 127.0f / rmax;
        int orow = rowbase + q * 4 + rg;
        if (orow < NN) {
#pragma unroll
            for (int t = 0; t < 8; t++) {
                int qi = __float2int_rn(acc[t][rg] * inv);
                m8[(size_t)orow * HID + t * 16 + r16] = (signed char)qi;
            }
            if (r16 == 0) sc[orow] = scale;
        }
    }
}

// ---------------- fused dispatches (role-STRIPED: 1 compute per 4 atomic blocks) ----------------

// phase 1: deg atomics || inproj || wpack, interleaved so both populations are
// co-resident on every CU from t=0 (atomic pipe || VALU pipe co-scheduling).
__global__ __launch_bounds__(256) void k_pre(const int* __restrict__ ei,
                                             const float* __restrict__ ew,
                                             unsigned long long* __restrict__ pk,
                                             int* __restrict__ ord,
                                             const float* __restrict__ x,
                                             const float* __restrict__ W_in,
                                             const float* __restrict__ b_in,
                                             float* __restrict__ h,
                                             const float* __restrict__ cW,
                                             ushort* __restrict__ Wp) {
    int c = blockIdx.x / 5;
    int r = blockIdx.x % 5;
    if (r == 0) {                      // compute role: 814 blocks
        if (c < NB_INP) do_inproj(c, x, W_in, b_in, h);
        else if (c < NB_C1) do_wpack(c - NB_INP, cW, Wp);
    } else {                           // atomic role
        int db = c * 4 + (r - 1);
        if (db < NB_DEG) do_deg(db, ei, ew, pk, ord);
    }
}

// phase 2: scatter || gemm layer 0, striped the same way (grid = 782*5 = 3910;
// scatter slots = 782*4 = 3128 >= 3125)
__global__ __launch_bounds__(256) void k_scat_gemm(const int* __restrict__ ei,
                                                   const float* __restrict__ ew,
                                                   const float* __restrict__ dinv,
                                                   const int* __restrict__ rowp,
                                                   const int* __restrict__ ord,
                                                   uint* __restrict__ erec,
                                                   const float* __restrict__ h,
                                                   const ushort* __restrict__ Wp,
                                                   signed char* __restrict__ m8,
                                                   float* __restrict__ sc) {
    int c = blockIdx.x / 5;
    int r = blockIdx.x % 5;
    if (r == 0) {
        do_gemm(c, h, Wp, m8, sc);     // c < 782 by grid construction
    } else {
        int sb = c * 4 + (r - 1);
        if (sb < NB_SCAT) do_scatter(sb, ei, ew, dinv, rowp, ord, erec);
    }
}

// ---------------- standalone kernels ----------------

__global__ void k_zero(int4* __restrict__ p, int n4) {
    int i = blockIdx.x * blockDim.x + threadIdx.x;
    if (i < n4) p[i] = make_int4(0, 0, 0, 0);
}

// hierarchical scan of padded counts ((cnt+7)&~7) -> rowp (exclusive); fused dinv
__global__ __launch_bounds__(1024) void k_scan_a(const unsigned long long* __restrict__ pk,
                                                 int* __restrict__ rowp_tmp,
                                                 int* __restrict__ bsum,
                                                 float* __restrict__ dinv) {
    __shared__ int wsum[16];
    int tid = threadIdx.x;
    int lane = tid & 63, wv = tid >> 6;
    int i = blockIdx.x * 1024 + tid;
    unsigned long long pv = (i < NN) ? pk[i] : 0ULL;
    if (i < NN) {
        float deg = (float)(unsigned int)(pv & 0xffffffffu) * (1.0f / WSCALE);
        dinv[i] = rsqrtf(deg + 1.0f);
    }
    int v = (((int)(pv >> 32) + 7) & ~7);
    int s = v;
#pragma unroll
    for (int off = 1; off < 64; off <<= 1) {
        int t = __shfl_up(s, off, 64);
        if (lane >= off) s += t;
    }
    if (lane == 63) wsum[wv] = s;
    __syncthreads();
    int woff = 0;
    for (int w = 0; w < wv; w++) woff += wsum[w];
    if (i < NN) rowp_tmp[i] = woff + s - v;
    if (tid == 1023) bsum[blockIdx.x] = woff + s;
}

__global__ __launch_bounds__(64) void k_scan_b(const int* __restrict__ bsum,
                                               int* __restrict__ boff,
                                               int* __restrict__ rowp, int nb) {
    int t = threadIdx.x;
    int v = (t < nb) ? bsum[t] : 0;
    int s = v;
#pragma unroll
    for (int off = 1; off < 64; off <<= 1) {
        int u = __shfl_up(s, off, 64);
        if (t >= off) s += u;
    }
    if (t < nb) boff[t] = s - v;
    if (t == 63) rowp[NN] = s;
}

// phase c: finalize rowp AND zero the padding slots (fused k_pad)
__global__ __launch_bounds__(1024) void k_scan_c(const int* __restrict__ rowp_tmp,
                                                 const int* __restrict__ boff,
                                                 const unsigned long long* __restrict__ pk,
                                                 int* __restrict__ rowp,
                                                 uint* __restrict__ erec) {
    int i = blockIdx.x * 1024 + threadIdx.x;
    if (i >= NN) return;
    int start = rowp_tmp[i] + boff[blockIdx.x];
    rowp[i] = start;
    int cnt = (int)(pk[i] >> 32);
    int v = (cnt + 7) & ~7;
    for (int p = start + cnt; p < start + v; p++) erec[p] = 0u;
}

__global__ __launch_bounds__(256) void k_gemm(const float* __restrict__ h,
                                              const ushort* __restrict__ Wp,
                                              signed char* __restrict__ m8,
                                              float* __restrict__ sc) {
    do_gemm(blockIdx.x, h, Wp, m8, sc);
}

// ---------------- aggregate + bias + LN + relu + residual (in-place h) ----------------
__global__ __launch_bounds__(256) void k_agg(const signed char* __restrict__ m8,
                                             const float* __restrict__ sc,
                                             const int* __restrict__ rowp,
                                             const uint* __restrict__ erec,
                                             const float* __restrict__ dinv,
                                             const float* __restrict__ cb,
                                             const float* __restrict__ g,
                                             const float* __restrict__ bb,
                                             float* __restrict__ h) {
    int lane = threadIdx.x & 63;
    int sub = lane & 31;           // channel quad: 4*sub..4*sub+3
    int hi = lane >> 5;            // which edge of the pair
    int n = blockIdx.x * 4 + (threadIdx.x >> 6);
    if (n >= NN) return;
    const uint* mu = (const uint*)m8;
    float dn = dinv[n];
    float selfs = hi ? 0.0f : dn * dn * sc[n];
    float4 sv = i8u(mu[(size_t)n * 32 + sub]);
    float4 a0, a1, a2, a3;
    a0.x = selfs * sv.x; a0.y = selfs * sv.y; a0.z = selfs * sv.z; a0.w = selfs * sv.w;
    a1 = make_float4(0, 0, 0, 0);
    a2 = make_float4(0, 0, 0, 0);
    a3 = make_float4(0, 0, 0, 0);
    int r0 = rowp[n], r1 = rowp[n + 1];          // multiples of 8
    const uint4* e4 = (const uint4*)erec;
    for (int r = r0; r < r1; r += 8) {
        int qb = r >> 2;
        uint4 rA = e4[qb + 0];                   // edges r .. r+3
        uint4 rB = e4[qb + 1];                   // edges r+4 .. r+7
        uint c0 = hi ? rA.y : rA.x;
        uint c1 = hi ? rA.w : rA.z;
        uint c2 = hi ? rB.y : rB.x;
        uint c3 = hi ? rB.w : rB.z;
        int s0 = c0 >> 15;  int s1 = c1 >> 15;
        int s2 = c2 >> 15;  int s3 = c3 >> 15;
        float v0 = (float)(c0 & 32767u) * (1.0f / VSCALE) * sc[s0];
        float v1 = (float)(c1 & 32767u) * (1.0f / VSCALE) * sc[s1];
        float v2 = (float)(c2 & 32767u) * (1.0f / VSCALE) * sc[s2];
        float v3 = (float)(c3 & 32767u) * (1.0f / VSCALE) * sc[s3];
        float4 f0 = i8u(mu[(size_t)s0 * 32 + sub]);
        float4 f1 = i8u(mu[(size_t)s1 * 32 + sub]);
        float4 f2 = i8u(mu[(size_t)s2 * 32 + sub]);
        float4 f3 = i8u(mu[(size_t)s3 * 32 + sub]);
        a0.x += v0 * f0.x; a0.y += v0 * f0.y; a0.z += v0 * f0.z; a0.w += v0 * f0.w;
        a1.x += v1 * f1.x; a1.y += v1 * f1.y; a1.z += v1 * f1.z; a1.w += v1 * f1.w;
        a2.x += v2 * f2.x; a2.y += v2 * f2.y; a2.z += v2 * f2.z; a2.w += v2 * f2.w;
        a3.x += v3 * f3.x; a3.y += v3 * f3.y; a3.z += v3 * f3.z; a3.w += v3 * f3.w;
    }
    float4 acc;
    acc.x = a0.x + a1.x + a2.x + a3.x;
    acc.y = a0.y + a1.y + a2.y + a3.y;
    acc.z = a0.z + a1.z + a2.z + a3.z;
    acc.w = a0.w + a1.w + a2.w + a3.w;
    acc.x += __shfl_xor(acc.x, 32, 64);
    acc.y += __shfl_xor(acc.y, 32, 64);
    acc.z += __shfl_xor(acc.z, 32, 64);
    acc.w += __shfl_xor(acc.w, 32, 64);
    float4 cbv = ((const float4*)cb)[sub];
    acc.x += cbv.x; acc.y += cbv.y; acc.z += cbv.z; acc.w += cbv.w;
    float s1 = acc.x + acc.y + acc.z + acc.w;
    float s2 = acc.x * acc.x + acc.y * acc.y + acc.z * acc.z + acc.w * acc.w;
#pragma unroll
    for (int off = 16; off > 0; off >>= 1) {
        s1 += __shfl_down(s1, off, 32);
        s2 += __shfl_down(s2, off, 32);
    }
    s1 = __shfl(s1, 0, 32);
    s2 = __shfl(s2, 0, 32);
    float mu_ = s1 * (1.0f / HID);
    float var = s2 * (1.0f / HID) - mu_ * mu_;
    float rs = rsqrtf(var + LN_EPS);
    if (hi == 0) {
        float4 gv = ((const float4*)g)[sub];
        float4 bv = ((const float4*)bb)[sub];
        float4* h4 = (float4*)h;
        float4 hv = h4[(size_t)n * 32 + sub];
        float4 o;
        o.x = fmaxf((acc.x - mu_) * rs * gv.x + bv.x, 0.f) + hv.x;
        o.y = fmaxf((acc.y - mu_) * rs * gv.y + bv.y, 0.f) + hv.y;
        o.z = fmaxf((acc.z - mu_) * rs * gv.z + bv.z, 0.f) + hv.z;
        o.w = fmaxf((acc.w - mu_) * rs * gv.w + bv.w, 0.f) + hv.w;
        h4[(size_t)n * 32 + sub] = o;
    }
}

// ---------------- launch ----------------

extern "C" void kernel_launch(void* const* d_in, const int* in_sizes, int n_in,
                              void* d_out, int out_size, void* d_ws, size_t ws_size,
                              hipStream_t stream) {
    const float* x    = (const float*)d_in[0];
    const int*   ei   = (const int*)d_in[1];
    const float* ew   = (const float*)d_in[2];
    const float* W_in = (const float*)d_in[3];
    const float* b_in = (const float*)d_in[4];
    const float* cW   = (const float*)d_in[5];
    const float* cb   = (const float*)d_in[6];
    const float* lg   = (const float*)d_in[7];
    const float* lb   = (const float*)d_in[8];
    float* h = (float*)d_out;

    char* ws = (char*)d_ws;
    unsigned long long* pk = (unsigned long long*)(ws + 0);   // 50000 u64 (400 KB)
    int*    rowp     = (int*)   (ws + 401408);                // 50001
    int*    rowp_tmp = (int*)   (ws + 602112);
    int*    bsum     = (int*)   (ws + 802816);                // 64
    int*    boff     = (int*)   (ws + 803072);                // 64
    uint*   erec     = (uint*)  (ws + 803328);                // ECAP u32 (4.6 MB)
    float*  dinv     = (float*) (ws + 5403328);               // 50000 f32
    ushort* Wp       = (ushort*)(ws + 5603328);               // 4*16384 bf16 (128 KB)
    signed char* m8  = (signed char*)(ws + 5734400);          // 50000*128 i8 (6.4 MB)
    float*  sc       = (float*) (ws + 12134400);              // 50000 f32 row scales
    int*    ord      = (int*)   (ws + 12334400);              // 800000 i32

    const int NB = (NN + 1023) / 1024;                        // 49

    k_zero<<<(100000 / 4 + 255) / 256, 256, 0, stream>>>((int4*)pk, 100000 / 4);
    // phase 1 (striped): deg atomics || input projection || W repack
    k_pre<<<NB_C1 * 5, 256, 0, stream>>>(ei, ew, pk, ord, x, W_in, b_in, h, cW, Wp);
    k_scan_a<<<NB, 1024, 0, stream>>>(pk, rowp_tmp, bsum, dinv);
    k_scan_b<<<1, 64, 0, stream>>>(bsum, boff, rowp, NB);
    k_scan_c<<<NB, 1024, 0, stream>>>(rowp_tmp, boff, pk, rowp, erec);
    // phase 2 (striped): edge scatter || layer-0 GEMM
    k_scat_gemm<<<NB_GEMM * 5, 256, 0, stream>>>(ei, ew, dinv, rowp, ord, erec,
                                                 h, Wp, m8, sc);

    k_agg<<<(NN + 3) / 4, 256, 0, stream>>>(m8, sc, rowp, erec, dinv,
                                            cb, lg, lb, h);
    for (int l = 1; l < NL; l++) {
        k_gemm<<<NB_GEMM, 256, 0, stream>>>(h, Wp + (size_t)l * 16384, m8, sc);
        k_agg<<<(NN + 3) / 4, 256, 0, stream>>>(m8, sc, rowp, erec, dinv,
                                                cb + l * HID, lg + l * HID, lb + l * HID, h);
    }
}